// Round 5
// baseline (1740.859 us; speedup 1.0000x reference)
//
#include <hip/hip_runtime.h>
#include <math.h>

#define NNODES 883
#define BB 8
#define DIMS_ 160
#define HID_ 320
#define RMAX (BB*NNODES)   // 7064 packed rows

// ---------------- patch assignment ----------------
__global__ __launch_bounds__(128)
void patch_kernel(const float* __restrict__ node_table,
                  const float* __restrict__ patch_emb,
                  float* __restrict__ probs_st,
                  float* __restrict__ nsoft,
                  int* __restrict__ patch_ids) {
  int n = blockIdx.x * blockDim.x + threadIdx.x;
  if (n >= NNODES) return;
  float nt[32];
#pragma unroll
  for (int j = 0; j < 32; ++j) nt[j] = node_table[n*32 + j];
  float lg[8];
#pragma unroll
  for (int r = 0; r < 8; ++r) {
    float a = 0.f;
#pragma unroll
    for (int j = 0; j < 32; ++j) a += nt[j] * patch_emb[r*32 + j];
    lg[r] = a;
  }
  float m = lg[0];
#pragma unroll
  for (int r = 1; r < 8; ++r) m = fmaxf(m, lg[r]);
  float e[8]; float s = 0.f;
#pragma unroll
  for (int r = 0; r < 8; ++r) { e[r] = expf(lg[r] - m); s += e[r]; }
  float p[8];
#pragma unroll
  for (int r = 0; r < 8; ++r) p[r] = e[r] / s;
  int am = 0; float best = p[0];
#pragma unroll
  for (int r = 1; r < 8; ++r) if (p[r] > best) { best = p[r]; am = r; }
  patch_ids[n] = am;
#pragma unroll
  for (int r = 0; r < 8; ++r) {
    float hard = (r == am) ? 1.f : 0.f;
    probs_st[n*8 + r] = (hard - p[r]) + p[r];
  }
#pragma unroll
  for (int j = 0; j < 32; ++j) {
    float a = 0.f;
#pragma unroll
    for (int r = 0; r < 8; ++r) a += p[r] * patch_emb[r*32 + j];
    nsoft[n*32 + j] = a;
  }
}

// ---------------- parallel scan ----------------
__global__ __launch_bounds__(1024)
void scan_kernel(const int* __restrict__ patch_ids,
                 int* __restrict__ pk, int* __restrict__ cnt,
                 int* __restrict__ offs, int* __restrict__ cntmax) {
  __shared__ int pid_s[NNODES];
  __shared__ int cnt_s[8], offs_s[8];
  int t = threadIdx.x;
  if (t < 8) cnt_s[t] = 0;
  for (int n = t; n < NNODES; n += 1024) pid_s[n] = patch_ids[n];
  __syncthreads();
  int p = -1, pos = 0;
  if (t < NNODES) {
    p = pid_s[t];
    atomicAdd(&cnt_s[p], 1);
    for (int m = 0; m < t; ++m) pos += (pid_s[m] == p) ? 1 : 0;
  }
  __syncthreads();
  if (t == 0) {
    int o = 0, mx = 0;
#pragma unroll
    for (int r = 0; r < 8; ++r) {
      offs_s[r] = o; offs[r] = o; o += cnt_s[r];
      cnt[r] = cnt_s[r];
      if (cnt_s[r] > mx) mx = cnt_s[r];
    }
    cntmax[0] = mx;
  }
  __syncthreads();
  if (t < NNODES) pk[t] = offs_s[p] + pos;
}

// ---------------- embedding ----------------
__global__ __launch_bounds__(160)
void embed_kernel(const float* __restrict__ x, const int* __restrict__ te,
                  const float* __restrict__ convW, const float* __restrict__ convB,
                  const float* __restrict__ tod, const float* __restrict__ dow,
                  const float* __restrict__ nsoft, const int* __restrict__ pk,
                  float* __restrict__ pf) {
  int n = blockIdx.x, b = blockIdx.y, t = threadIdx.x;
  __shared__ float xs[3][12];
  if (t < 12) {
    int l = t;
    xs[0][l] = x[(b*12 + l)*NNODES + n];
    int base = ((b*12 + l)*NNODES + n)*2;
    xs[1][l] = (float)te[base]     / 288.0f;
    xs[2][l] = (float)te[base + 1] / 7.0f;
  }
  __syncthreads();
  int row = b*NNODES + pk[n];
  float val;
  if (t < 64) {
    float a = convB[t];
#pragma unroll
    for (int c = 0; c < 3; ++c)
#pragma unroll
      for (int l = 0; l < 12; ++l)
        a += xs[c][l] * convW[t*36 + c*12 + l];
    val = a;
  } else if (t < 96) {
    int ti = te[((b*12 + 11)*NNODES + n)*2 + 0];
    val = tod[ti*32 + (t - 64)];
  } else if (t < 128) {
    int dw = te[((b*12 + 11)*NNODES + n)*2 + 1];
    val = dow[dw*32 + (t - 96)];
  } else {
    val = nsoft[n*32 + (t - 128)];
  }
  pf[row*DIMS_ + t] = val;
}

// ---------------- fused (optional LN) matmul: 32 rows x 160 cols per block ----------------
template<int K, int ACT, bool RESID, bool LN>
__global__ __launch_bounds__(256)
void matmul_ln(const float* __restrict__ X, const float* __restrict__ W,
               const float* __restrict__ bias, float* __restrict__ C,
               const float* __restrict__ g, const float* __restrict__ bt,
               int M, int Nfull, int Cstride,
               size_t Wystep, size_t Cystep, int bystep, int colstep) {
  constexpr int ROWS = 32;
  constexpr int STR = K + 1;
  __shared__ float Xs[ROWS * STR];
  __shared__ float gs[LN ? K : 1];
  __shared__ float bs[LN ? K : 1];
  int tid = threadIdx.x;
  int rowbase = blockIdx.x * ROWS;
  int y = blockIdx.y;
  W    += (size_t)y * Wystep;
  C    += (size_t)y * Cystep;
  bias += (size_t)y * bystep;
  int coloff = y * colstep;

  for (int idx = tid; idx < ROWS*(K/4); idx += 256) {
    int r = idx / (K/4), d4 = idx % (K/4);
    int gr = rowbase + r;
    float4 v;
    if (gr < M) v = *(const float4*)&X[(size_t)gr*K + d4*4];
    else        v = float4{0.f,0.f,0.f,0.f};
    Xs[r*STR + d4*4 + 0] = v.x; Xs[r*STR + d4*4 + 1] = v.y;
    Xs[r*STR + d4*4 + 2] = v.z; Xs[r*STR + d4*4 + 3] = v.w;
  }
  if (LN) {
    for (int k = tid; k < K; k += 256) { gs[k] = g[k]; bs[k] = bt[k]; }
  }
  __syncthreads();

  if (LN) {
    int r = tid >> 3, i = tid & 7;
    float s = 0.f, ss = 0.f;
    for (int k = i; k < K; k += 8) { float v = Xs[r*STR + k]; s += v; ss += v*v; }
    s += __shfl_xor(s, 1, 8); ss += __shfl_xor(ss, 1, 8);
    s += __shfl_xor(s, 2, 8); ss += __shfl_xor(ss, 2, 8);
    s += __shfl_xor(s, 4, 8); ss += __shfl_xor(ss, 4, 8);
    float mu = s / (float)K;
    float var = ss / (float)K - mu*mu;
    float rsig = rsqrtf(var + 1e-5f);
    for (int k = i; k < K; k += 8)
      Xs[r*STR + k] = (Xs[r*STR + k] - mu) * rsig * gs[k] + bs[k];
    __syncthreads();
  }

  int r = tid & 31, cg = tid >> 5;
  int gr = rowbase + r;
  bool valid = gr < M;
  const float* Xr = &Xs[r*STR];
#pragma unroll
  for (int i2 = 0; i2 < 5; ++i2) {
    int c = (cg + 8*i2) * 4;
    int gc = coloff + c;
    float4 acc = *(const float4*)&bias[c + coloff];
#pragma unroll 8
    for (int k = 0; k < K; ++k) {
      float xv = Xr[k];
      float4 w4 = *(const float4*)&W[(size_t)k*Nfull + gc];
      acc.x += xv * w4.x; acc.y += xv * w4.y;
      acc.z += xv * w4.z; acc.w += xv * w4.w;
    }
    if (ACT == 1) {
      acc.x = 0.5f*acc.x*(1.f + erff(acc.x*0.70710678118654752f));
      acc.y = 0.5f*acc.y*(1.f + erff(acc.y*0.70710678118654752f));
      acc.z = 0.5f*acc.z*(1.f + erff(acc.z*0.70710678118654752f));
      acc.w = 0.5f*acc.w*(1.f + erff(acc.w*0.70710678118654752f));
    }
    if (valid) {
      float* Cr = &C[(size_t)gr*Cstride + gc];
      if (RESID) {
        float4 old = *(const float4*)Cr;
        old.x += acc.x; old.y += acc.y; old.z += acc.z; old.w += acc.w;
        *(float4*)Cr = old;
      } else {
        *(float4*)Cr = acc;
      }
    }
  }
}

// ---------------- intra-patch attention ----------------
#define QT 16
#define KT 32
#define SMAX 256
#define TSTR 164

__global__ __launch_bounds__(256)
void intra_attn(const float* __restrict__ qb, const float* __restrict__ kb,
                const float* __restrict__ vb, float* __restrict__ ab,
                const int* __restrict__ cnt, const int* __restrict__ offs) {
  int r = blockIdx.y, b = blockIdx.z;
  int L = cnt[r];
  int qbase = blockIdx.x * QT;
  if (qbase >= L) return;
  int nq = min(QT, L - qbase);
  int bo = b*NNODES + offs[r];
  __shared__ float Qs[QT*TSTR];
  __shared__ float KVs[KT*TSTR];
  __shared__ float S[QT*SMAX];
  int tid = threadIdx.x;
  const float scale = 0.07905694150420949f;

  for (int idx = tid; idx < nq*40; idx += 256) {
    int q = idx/40, d4 = idx%40;
    *(float4*)&Qs[q*TSTR + d4*4] =
        *(const float4*)&qb[(size_t)(bo+qbase+q)*DIMS_ + d4*4];
  }

  int nkt = (L + KT - 1)/KT;
  for (int kt = 0; kt < nkt; ++kt) {
    int jbase = kt*KT;
    int nj = min(KT, L - jbase);
    __syncthreads();
    for (int idx = tid; idx < nj*40; idx += 256) {
      int j = idx/40, d4 = idx%40;
      *(float4*)&KVs[j*TSTR + d4*4] =
          *(const float4*)&kb[(size_t)(bo+jbase+j)*DIMS_ + d4*4];
    }
    __syncthreads();
#pragma unroll
    for (int p = tid; p < 512; p += 256) {
      int q = p >> 5, j = p & 31;
      if (q < nq && j < nj) {
        const float* Qr = &Qs[q*TSTR];
        const float* Kr = &KVs[j*TSTR];
        float ax=0.f, ay=0.f, az=0.f, aw=0.f;
#pragma unroll
        for (int d4 = 0; d4 < 40; ++d4) {
          float4 a = *(const float4*)&Qr[d4*4];
          float4 c = *(const float4*)&Kr[d4*4];
          ax += a.x*c.x; ay += a.y*c.y; az += a.z*c.z; aw += a.w*c.w;
        }
        S[q*SMAX + jbase + j] = (ax+ay+az+aw) * scale;
      }
    }
  }
  __syncthreads();

  {
    int q = tid >> 4, i = tid & 15;
    float m = -INFINITY;
    if (q < nq)
      for (int j = i; j < L; j += 16) m = fmaxf(m, S[q*SMAX + j]);
    m = fmaxf(m, __shfl_xor(m, 1, 16));
    m = fmaxf(m, __shfl_xor(m, 2, 16));
    m = fmaxf(m, __shfl_xor(m, 4, 16));
    m = fmaxf(m, __shfl_xor(m, 8, 16));
    float s = 0.f;
    if (q < nq)
      for (int j = i; j < L; j += 16) {
        float e = expf(S[q*SMAX + j] - m);
        S[q*SMAX + j] = e; s += e;
      }
    s += __shfl_xor(s, 1, 16);
    s += __shfl_xor(s, 2, 16);
    s += __shfl_xor(s, 4, 16);
    s += __shfl_xor(s, 8, 16);
    float inv = 1.f / s;
    if (q < nq)
      for (int j = i; j < L; j += 16) S[q*SMAX + j] *= inv;
  }

  float o[10];
#pragma unroll
  for (int u = 0; u < 10; ++u) o[u] = 0.f;
  int q = tid >> 4, dg = tid & 15;
  for (int kt = 0; kt < nkt; ++kt) {
    int jbase = kt*KT;
    int nj = min(KT, L - jbase);
    __syncthreads();
    for (int idx = tid; idx < nj*40; idx += 256) {
      int j = idx/40, d4 = idx%40;
      *(float4*)&KVs[j*TSTR + d4*4] =
          *(const float4*)&vb[(size_t)(bo+jbase+j)*DIMS_ + d4*4];
    }
    __syncthreads();
    if (q < nq) {
      for (int j = 0; j < nj; ++j) {
        float w = S[q*SMAX + jbase + j];
        const float* Vr = &KVs[j*TSTR + dg];
#pragma unroll
        for (int u = 0; u < 10; ++u) o[u] += w * Vr[16*u];
      }
    }
  }
  if (q < nq) {
    float* Ar = &ab[(size_t)(bo+qbase+q)*DIMS_ + dg];
#pragma unroll
    for (int u = 0; u < 10; ++u) Ar[16*u] = o[u];
  }
}

// ---------------- inter-patch attention ----------------
__global__ __launch_bounds__(64)
void inter_attn(const float* __restrict__ qb, const float* __restrict__ kb,
                const float* __restrict__ vb, float* __restrict__ ab,
                const int* __restrict__ cnt, const int* __restrict__ offs,
                const int* __restrict__ cntmax) {
  int p = blockIdx.x, b = blockIdx.y;
  if (p >= cntmax[0]) return;
  int t = threadIdx.x;
  __shared__ int rows[8];
  __shared__ int nvs;
  __shared__ float w[8][9];
  if (t == 0) {
    int nv = 0;
    for (int r = 0; r < 8; ++r)
      if (p < cnt[r]) rows[nv++] = b*NNODES + offs[r] + p;
    nvs = nv;
  }
  __syncthreads();
  int nv = nvs;
  const float scale = 0.07905694150420949f;
  int i = t >> 3, j = t & 7;
  if (i < nv && j < nv) {
    const float4* qr = (const float4*)&qb[(size_t)rows[i]*DIMS_];
    const float4* kr = (const float4*)&kb[(size_t)rows[j]*DIMS_];
    float ax=0.f, ay=0.f, az=0.f, aw=0.f;
#pragma unroll
    for (int d4 = 0; d4 < 40; ++d4) {
      float4 a = qr[d4], c = kr[d4];
      ax += a.x*c.x; ay += a.y*c.y; az += a.z*c.z; aw += a.w*c.w;
    }
    w[i][j] = (ax+ay+az+aw) * scale;
  }
  __syncthreads();
  if (t < nv) {
    float m = -INFINITY;
    for (int jj = 0; jj < nv; ++jj) m = fmaxf(m, w[t][jj]);
    float s = 0.f;
    for (int jj = 0; jj < nv; ++jj) { float e = expf(w[t][jj] - m); w[t][jj] = e; s += e; }
    float inv = 1.0f / s;
    for (int jj = 0; jj < nv; ++jj) w[t][jj] *= inv;
  }
  __syncthreads();
  for (int d4 = t; d4 < 40; d4 += 64) {
    for (int i2 = 0; i2 < nv; ++i2) {
      float4 a = {0.f,0.f,0.f,0.f};
      for (int j2 = 0; j2 < nv; ++j2) {
        float ww = w[i2][j2];
        float4 v4 = *(const float4*)&vb[(size_t)rows[j2]*DIMS_ + d4*4];
        a.x += ww*v4.x; a.y += ww*v4.y; a.z += ww*v4.z; a.w += ww*v4.w;
      }
      *(float4*)&ab[(size_t)rows[i2]*DIMS_ + d4*4] = a;
    }
  }
}

// ---------------- final projection ----------------
__global__ __launch_bounds__(256)
void out_kernel(const float* __restrict__ pf, const float* __restrict__ outW,
                const float* __restrict__ outB, const int* __restrict__ pk,
                float* __restrict__ out) {
  int idx = blockIdx.x*256 + threadIdx.x;
  if (idx >= BB*12*NNODES) return;
  int n = idx % NNODES;
  int rest = idx / NNODES;
  int o = rest % 12;
  int b = rest / 12;
  int row = b*NNODES + pk[n];
  const float4* Pr = (const float4*)&pf[(size_t)row*DIMS_];
  const float4* Wr = (const float4*)&outW[o*DIMS_];
  float ax=0.f, ay=0.f, az=0.f, aw=0.f;
#pragma unroll
  for (int d4 = 0; d4 < 40; ++d4) {
    float4 a = Pr[d4], c = Wr[d4];
    ax += a.x*c.x; ay += a.y*c.y; az += a.z*c.z; aw += a.w*c.w;
  }
  out[idx] = (ax+ay+az+aw) + outB[o];
}

extern "C" void kernel_launch(void* const* d_in, const int* in_sizes, int n_in,
                              void* d_out, int out_size, void* d_ws, size_t ws_size,
                              hipStream_t stream) {
  const float* x         = (const float*)d_in[0];
  const int*   te        = (const int*)d_in[1];
  const float* patch_emb = (const float*)d_in[2];
  const float* node_tab  = (const float*)d_in[3];
  const float* tod_emb   = (const float*)d_in[4];
  const float* dow_emb   = (const float*)d_in[5];
  const float* conv_W    = (const float*)d_in[6];
  const float* conv_b    = (const float*)d_in[7];
  const float* ln_scale  = (const float*)d_in[8];
  const float* ln_bias   = (const float*)d_in[9];
  const float* attn_W    = (const float*)d_in[10];
  const float* attn_b    = (const float*)d_in[11];
  const float* mlp_W1    = (const float*)d_in[12];
  const float* mlp_b1    = (const float*)d_in[13];
  const float* mlp_W2    = (const float*)d_in[14];
  const float* mlp_b2    = (const float*)d_in[15];
  const float* out_W     = (const float*)d_in[16];
  const float* out_b     = (const float*)d_in[17];

  float* out = (float*)d_out;
  float* probs_st = out + BB*12*NNODES;

  float* ws = (float*)d_ws;
  float* pf  = ws;
  float* qb  = pf  + (size_t)RMAX*DIMS_;
  float* kb  = qb  + (size_t)RMAX*DIMS_;
  float* vb  = kb  + (size_t)RMAX*DIMS_;
  float* ab2 = vb  + (size_t)RMAX*DIMS_;
  float* hb  = ab2 + (size_t)RMAX*DIMS_;
  float* nsoft = hb + (size_t)RMAX*HID_;
  int* patch_ids = (int*)(nsoft + NNODES*32);
  int* pk     = patch_ids + NNODES;
  int* cnt    = pk + NNODES;
  int* offs   = cnt + 8;
  int* cntmax = offs + 8;

  patch_kernel<<<(NNODES + 127)/128, 128, 0, stream>>>(node_tab, patch_emb, probs_st, nsoft, patch_ids);
  scan_kernel<<<1, 1024, 0, stream>>>(patch_ids, pk, cnt, offs, cntmax);
  embed_kernel<<<dim3(NNODES, BB), 160, 0, stream>>>(x, te, conv_W, conv_b, tod_emb, dow_emb, nsoft, pk, pf);

  const int GRIDR = (RMAX + 31)/32;   // 221

  for (int l = 0; l < 3; ++l) {
    for (int a = 0; a < 2; ++a) {
      int wb = l*2 + a;
      const float* Wbase = attn_W + (size_t)wb*4*DIMS_*DIMS_;
      const float* bbase = attn_b + (size_t)wb*4*DIMS_;
      const float* g0 = ln_scale + (size_t)(l*4 + a*2)*DIMS_;
      const float* b0 = ln_bias  + (size_t)(l*4 + a*2)*DIMS_;
      const float* g1 = ln_scale + (size_t)(l*4 + a*2 + 1)*DIMS_;
      const float* b1 = ln_bias  + (size_t)(l*4 + a*2 + 1)*DIMS_;

      // QKV fused: y in {0,1,2} -> W offset, bias offset, output buffer offset
      matmul_ln<160,0,false,true><<<dim3(GRIDR,3), 256, 0, stream>>>(
          pf, Wbase, bbase, qb, g0, b0,
          RMAX, DIMS_, DIMS_,
          (size_t)DIMS_*DIMS_, (size_t)RMAX*DIMS_, DIMS_, 0);

      if (a == 0)
        intra_attn<<<dim3(SMAX/QT, 8, BB), 256, 0, stream>>>(qb, kb, vb, ab2, cnt, offs);
      else
        inter_attn<<<dim3(NNODES, BB), 64, 0, stream>>>(qb, kb, vb, ab2, cnt, offs, cntmax);

      // proj + residual into pf
      matmul_ln<160,0,true,false><<<dim3(GRIDR,1), 256, 0, stream>>>(
          ab2, Wbase + 3*DIMS_*DIMS_, bbase + 3*DIMS_, pf, nullptr, nullptr,
          RMAX, DIMS_, DIMS_, 0, 0, 0, 0);

      // MLP1: LN(pf) @ W1 -> hb (gelu); N=320 split over y in {0,1}
      matmul_ln<160,1,false,true><<<dim3(GRIDR,2), 256, 0, stream>>>(
          pf, mlp_W1 + (size_t)wb*DIMS_*HID_, mlp_b1 + (size_t)wb*HID_, hb, g1, b1,
          RMAX, HID_, HID_, 0, 0, 0, DIMS_);

      // MLP2: hb @ W2 + residual into pf
      matmul_ln<320,0,true,false><<<dim3(GRIDR,1), 256, 0, stream>>>(
          hb, mlp_W2 + (size_t)wb*HID_*DIMS_, mlp_b2 + (size_t)wb*DIMS_, pf, nullptr, nullptr,
          RMAX, DIMS_, DIMS_, 0, 0, 0, 0);
    }
  }

  out_kernel<<<(BB*12*NNODES + 255)/256, 256, 0, stream>>>(pf, out_W, out_b, pk, out);
}

// Round 6
// 688.201 us; speedup vs baseline: 2.5296x; 2.5296x over previous
//
#include <hip/hip_runtime.h>
#include <math.h>

#define NNODES 883
#define BB 8
#define DIMS_ 160
#define HID_ 320
#define RMAX (BB*NNODES)   // 7064 packed rows

typedef __attribute__((ext_vector_type(8))) short short8v;   // 8 bf16 in 4 VGPRs
typedef __attribute__((ext_vector_type(4))) float fx4;

__device__ __forceinline__ unsigned short f2bf(float f) {
  unsigned int u = __float_as_uint(f);
  u = (u + 0x7fffu + ((u >> 16) & 1u)) >> 16;   // RNE
  return (unsigned short)u;
}

// ---------------- patch assignment ----------------
__global__ __launch_bounds__(128)
void patch_kernel(const float* __restrict__ node_table,
                  const float* __restrict__ patch_emb,
                  float* __restrict__ probs_st,
                  float* __restrict__ nsoft,
                  int* __restrict__ patch_ids) {
  int n = blockIdx.x * blockDim.x + threadIdx.x;
  if (n >= NNODES) return;
  float nt[32];
#pragma unroll
  for (int j = 0; j < 32; ++j) nt[j] = node_table[n*32 + j];
  float lg[8];
#pragma unroll
  for (int r = 0; r < 8; ++r) {
    float a = 0.f;
#pragma unroll
    for (int j = 0; j < 32; ++j) a += nt[j] * patch_emb[r*32 + j];
    lg[r] = a;
  }
  float m = lg[0];
#pragma unroll
  for (int r = 1; r < 8; ++r) m = fmaxf(m, lg[r]);
  float e[8]; float s = 0.f;
#pragma unroll
  for (int r = 0; r < 8; ++r) { e[r] = expf(lg[r] - m); s += e[r]; }
  float p[8];
#pragma unroll
  for (int r = 0; r < 8; ++r) p[r] = e[r] / s;
  int am = 0; float best = p[0];
#pragma unroll
  for (int r = 1; r < 8; ++r) if (p[r] > best) { best = p[r]; am = r; }
  patch_ids[n] = am;
#pragma unroll
  for (int r = 0; r < 8; ++r) {
    float hard = (r == am) ? 1.f : 0.f;
    probs_st[n*8 + r] = (hard - p[r]) + p[r];
  }
#pragma unroll
  for (int j = 0; j < 32; ++j) {
    float a = 0.f;
#pragma unroll
    for (int r = 0; r < 8; ++r) a += p[r] * patch_emb[r*32 + j];
    nsoft[n*32 + j] = a;
  }
}

// ---------------- parallel scan ----------------
__global__ __launch_bounds__(1024)
void scan_kernel(const int* __restrict__ patch_ids,
                 int* __restrict__ pk, int* __restrict__ cnt,
                 int* __restrict__ offs, int* __restrict__ cntmax) {
  __shared__ int pid_s[NNODES];
  __shared__ int cnt_s[8], offs_s[8];
  int t = threadIdx.x;
  if (t < 8) cnt_s[t] = 0;
  for (int n = t; n < NNODES; n += 1024) pid_s[n] = patch_ids[n];
  __syncthreads();
  int p = -1, pos = 0;
  if (t < NNODES) {
    p = pid_s[t];
    atomicAdd(&cnt_s[p], 1);
    for (int m = 0; m < t; ++m) pos += (pid_s[m] == p) ? 1 : 0;
  }
  __syncthreads();
  if (t == 0) {
    int o = 0, mx = 0;
#pragma unroll
    for (int r = 0; r < 8; ++r) {
      offs_s[r] = o; offs[r] = o; o += cnt_s[r];
      cnt[r] = cnt_s[r];
      if (cnt_s[r] > mx) mx = cnt_s[r];
    }
    cntmax[0] = mx;
  }
  __syncthreads();
  if (t < NNODES) pk[t] = offs_s[p] + pos;
}

// ---------------- embedding ----------------
__global__ __launch_bounds__(160)
void embed_kernel(const float* __restrict__ x, const int* __restrict__ te,
                  const float* __restrict__ convW, const float* __restrict__ convB,
                  const float* __restrict__ tod, const float* __restrict__ dow,
                  const float* __restrict__ nsoft, const int* __restrict__ pk,
                  float* __restrict__ pf) {
  int n = blockIdx.x, b = blockIdx.y, t = threadIdx.x;
  __shared__ float xs[3][12];
  if (t < 12) {
    int l = t;
    xs[0][l] = x[(b*12 + l)*NNODES + n];
    int base = ((b*12 + l)*NNODES + n)*2;
    xs[1][l] = (float)te[base]     / 288.0f;
    xs[2][l] = (float)te[base + 1] / 7.0f;
  }
  __syncthreads();
  int row = b*NNODES + pk[n];
  float val;
  if (t < 64) {
    float a = convB[t];
#pragma unroll
    for (int c = 0; c < 3; ++c)
#pragma unroll
      for (int l = 0; l < 12; ++l)
        a += xs[c][l] * convW[t*36 + c*12 + l];
    val = a;
  } else if (t < 96) {
    int ti = te[((b*12 + 11)*NNODES + n)*2 + 0];
    val = tod[ti*32 + (t - 64)];
  } else if (t < 128) {
    int dw = te[((b*12 + 11)*NNODES + n)*2 + 1];
    val = dow[dw*32 + (t - 96)];
  } else {
    val = nsoft[n*32 + (t - 128)];
  }
  pf[row*DIMS_ + t] = val;
}

// ---------------- weight convert + transpose to bf16 [N][K] ----------------
__global__ __launch_bounds__(256)
void cvt_w_kernel(const float* __restrict__ src, unsigned short* __restrict__ dst,
                  int K, int N) {
  size_t base = (size_t)blockIdx.y * K * N;
  int total = K * N;
  for (int idx = blockIdx.x*256 + threadIdx.x; idx < total; idx += gridDim.x*256) {
    int n = idx / K, k = idx - n*K;
    dst[base + idx] = f2bf(src[base + (size_t)k*N + n]);
  }
}

// ---------------- MFMA matmul: one wave computes 16 rows x 80 cols ----------------
// X f32 [M][K]; Wt bf16 [Ntot][K] (transposed); C f32 [M][Cstride].
// blockIdx.x: row tile (16 rows); blockIdx.y: col half (80 cols); blockIdx.z: slice
// (Wt += z*Wystep, C += z*Cystep, bias += z*bystep).
template<int K, int ACT, bool RESID, bool LN>
__global__ __launch_bounds__(64)
void mfma_mm(const float* __restrict__ X, const unsigned short* __restrict__ Wt,
             const float* __restrict__ bias, float* __restrict__ C,
             const float* __restrict__ g, const float* __restrict__ bt,
             int M, int Cstride, size_t Wystep, size_t Cystep, int bystep) {
  constexpr int NS = K / 32;
  int lane = threadIdx.x;
  int r15  = lane & 15;
  int kg   = lane >> 4;            // 0..3
  int row0 = blockIdx.x * 16;
  int colbase = blockIdx.y * 80;
  int z = blockIdx.z;
  Wt   += (size_t)z * Wystep;
  C    += (size_t)z * Cystep;
  bias += (size_t)z * bystep;

  int ar = row0 + r15; if (ar > M-1) ar = M-1;
  const float* Xr = X + (size_t)ar*K + kg*8;

  short8v afrag[NS];
  if (LN) {
    float av[8*NS];
    float s = 0.f, ss = 0.f;
#pragma unroll
    for (int t = 0; t < NS; ++t) {
      float4 v0 = *(const float4*)(Xr + t*32);
      float4 v1 = *(const float4*)(Xr + t*32 + 4);
      float* a = &av[t*8];
      a[0]=v0.x; a[1]=v0.y; a[2]=v0.z; a[3]=v0.w;
      a[4]=v1.x; a[5]=v1.y; a[6]=v1.z; a[7]=v1.w;
#pragma unroll
      for (int j = 0; j < 8; ++j) { s += a[j]; ss += a[j]*a[j]; }
    }
    s  += __shfl_xor(s, 16);  ss += __shfl_xor(ss, 16);
    s  += __shfl_xor(s, 32);  ss += __shfl_xor(ss, 32);
    float mu  = s * (1.0f/(float)K);
    float var = ss * (1.0f/(float)K) - mu*mu;
    float rsig = rsqrtf(var + 1e-5f);
#pragma unroll
    for (int t = 0; t < NS; ++t) {
      int kb = t*32 + kg*8;
      float4 g0 = *(const float4*)(g + kb);
      float4 g1 = *(const float4*)(g + kb + 4);
      float4 b0 = *(const float4*)(bt + kb);
      float4 b1 = *(const float4*)(bt + kb + 4);
      float gv[8] = {g0.x,g0.y,g0.z,g0.w,g1.x,g1.y,g1.z,g1.w};
      float bv[8] = {b0.x,b0.y,b0.z,b0.w,b1.x,b1.y,b1.z,b1.w};
      short8v f;
#pragma unroll
      for (int j = 0; j < 8; ++j) {
        float nv = (av[t*8 + j] - mu) * rsig * gv[j] + bv[j];
        f[j] = (short)f2bf(nv);
      }
      afrag[t] = f;
    }
  } else {
#pragma unroll
    for (int t = 0; t < NS; ++t) {
      float4 v0 = *(const float4*)(Xr + t*32);
      float4 v1 = *(const float4*)(Xr + t*32 + 4);
      short8v f;
      f[0]=(short)f2bf(v0.x); f[1]=(short)f2bf(v0.y);
      f[2]=(short)f2bf(v0.z); f[3]=(short)f2bf(v0.w);
      f[4]=(short)f2bf(v1.x); f[5]=(short)f2bf(v1.y);
      f[6]=(short)f2bf(v1.z); f[7]=(short)f2bf(v1.w);
      afrag[t] = f;
    }
  }

  fx4 acc[5];
#pragma unroll
  for (int n = 0; n < 5; ++n) acc[n] = (fx4){0.f,0.f,0.f,0.f};

  const unsigned short* Wb = Wt + (size_t)(colbase + r15)*K + kg*8;
#pragma unroll
  for (int t = 0; t < NS; ++t) {
#pragma unroll
    for (int n = 0; n < 5; ++n) {
      short8v bfr = *(const short8v*)(const void*)(Wb + (size_t)n*16*K + t*32);
      acc[n] = __builtin_amdgcn_mfma_f32_16x16x32_bf16(afrag[t], bfr, acc[n], 0, 0, 0);
    }
  }

  int orow0 = row0 + kg*4;
#pragma unroll
  for (int n = 0; n < 5; ++n) {
    int col = colbase + n*16 + r15;
    float bv = bias[col];
#pragma unroll
    for (int i = 0; i < 4; ++i) {
      int rr = orow0 + i;
      if (rr >= M) continue;
      float v = acc[n][i] + bv;
      if (ACT == 1) v = 0.5f*v*(1.f + erff(v*0.70710678118654752f));
      float* p = &C[(size_t)rr*Cstride + col];
      if (RESID) *p += v; else *p = v;
    }
  }
}

// ---------------- intra-patch attention ----------------
#define QT 16
#define KT 32
#define SMAX 256
#define TSTR 164

__global__ __launch_bounds__(256)
void intra_attn(const float* __restrict__ qb, const float* __restrict__ kb,
                const float* __restrict__ vb, float* __restrict__ ab,
                const int* __restrict__ cnt, const int* __restrict__ offs) {
  int r = blockIdx.y, b = blockIdx.z;
  int L = cnt[r];
  int qbase = blockIdx.x * QT;
  if (qbase >= L) return;
  int nq = min(QT, L - qbase);
  int bo = b*NNODES + offs[r];
  __shared__ float Qs[QT*TSTR];
  __shared__ float KVs[KT*TSTR];
  __shared__ float S[QT*SMAX];
  int tid = threadIdx.x;
  const float scale = 0.07905694150420949f;

  for (int idx = tid; idx < nq*40; idx += 256) {
    int q = idx/40, d4 = idx%40;
    *(float4*)&Qs[q*TSTR + d4*4] =
        *(const float4*)&qb[(size_t)(bo+qbase+q)*DIMS_ + d4*4];
  }

  int nkt = (L + KT - 1)/KT;
  for (int kt = 0; kt < nkt; ++kt) {
    int jbase = kt*KT;
    int nj = min(KT, L - jbase);
    __syncthreads();
    for (int idx = tid; idx < nj*40; idx += 256) {
      int j = idx/40, d4 = idx%40;
      *(float4*)&KVs[j*TSTR + d4*4] =
          *(const float4*)&kb[(size_t)(bo+jbase+j)*DIMS_ + d4*4];
    }
    __syncthreads();
#pragma unroll
    for (int p = tid; p < 512; p += 256) {
      int q = p >> 5, j = p & 31;
      if (q < nq && j < nj) {
        const float* Qr = &Qs[q*TSTR];
        const float* Kr = &KVs[j*TSTR];
        float ax=0.f, ay=0.f, az=0.f, aw=0.f;
#pragma unroll
        for (int d4 = 0; d4 < 40; ++d4) {
          float4 a = *(const float4*)&Qr[d4*4];
          float4 c = *(const float4*)&Kr[d4*4];
          ax += a.x*c.x; ay += a.y*c.y; az += a.z*c.z; aw += a.w*c.w;
        }
        S[q*SMAX + jbase + j] = (ax+ay+az+aw) * scale;
      }
    }
  }
  __syncthreads();

  {
    int q = tid >> 4, i = tid & 15;
    float m = -INFINITY;
    if (q < nq)
      for (int j = i; j < L; j += 16) m = fmaxf(m, S[q*SMAX + j]);
    m = fmaxf(m, __shfl_xor(m, 1, 16));
    m = fmaxf(m, __shfl_xor(m, 2, 16));
    m = fmaxf(m, __shfl_xor(m, 4, 16));
    m = fmaxf(m, __shfl_xor(m, 8, 16));
    float s = 0.f;
    if (q < nq)
      for (int j = i; j < L; j += 16) {
        float e = expf(S[q*SMAX + j] - m);
        S[q*SMAX + j] = e; s += e;
      }
    s += __shfl_xor(s, 1, 16);
    s += __shfl_xor(s, 2, 16);
    s += __shfl_xor(s, 4, 16);
    s += __shfl_xor(s, 8, 16);
    float inv = 1.f / s;
    if (q < nq)
      for (int j = i; j < L; j += 16) S[q*SMAX + j] *= inv;
  }

  float o[10];
#pragma unroll
  for (int u = 0; u < 10; ++u) o[u] = 0.f;
  int q = tid >> 4, dg = tid & 15;
  for (int kt = 0; kt < nkt; ++kt) {
    int jbase = kt*KT;
    int nj = min(KT, L - jbase);
    __syncthreads();
    for (int idx = tid; idx < nj*40; idx += 256) {
      int j = idx/40, d4 = idx%40;
      *(float4*)&KVs[j*TSTR + d4*4] =
          *(const float4*)&vb[(size_t)(bo+jbase+j)*DIMS_ + d4*4];
    }
    __syncthreads();
    if (q < nq) {
      for (int j = 0; j < nj; ++j) {
        float w = S[q*SMAX + jbase + j];
        const float* Vr = &KVs[j*TSTR + dg];
#pragma unroll
        for (int u = 0; u < 10; ++u) o[u] += w * Vr[16*u];
      }
    }
  }
  if (q < nq) {
    float* Ar = &ab[(size_t)(bo+qbase+q)*DIMS_ + dg];
#pragma unroll
    for (int u = 0; u < 10; ++u) Ar[16*u] = o[u];
  }
}

// ---------------- inter-patch attention ----------------
__global__ __launch_bounds__(64)
void inter_attn(const float* __restrict__ qb, const float* __restrict__ kb,
                const float* __restrict__ vb, float* __restrict__ ab,
                const int* __restrict__ cnt, const int* __restrict__ offs,
                const int* __restrict__ cntmax) {
  int p = blockIdx.x, b = blockIdx.y;
  if (p >= cntmax[0]) return;
  int t = threadIdx.x;
  __shared__ int rows[8];
  __shared__ int nvs;
  __shared__ float w[8][9];
  if (t == 0) {
    int nv = 0;
    for (int r = 0; r < 8; ++r)
      if (p < cnt[r]) rows[nv++] = b*NNODES + offs[r] + p;
    nvs = nv;
  }
  __syncthreads();
  int nv = nvs;
  const float scale = 0.07905694150420949f;
  int i = t >> 3, j = t & 7;
  if (i < nv && j < nv) {
    const float4* qr = (const float4*)&qb[(size_t)rows[i]*DIMS_];
    const float4* kr = (const float4*)&kb[(size_t)rows[j]*DIMS_];
    float ax=0.f, ay=0.f, az=0.f, aw=0.f;
#pragma unroll
    for (int d4 = 0; d4 < 40; ++d4) {
      float4 a = qr[d4], c = kr[d4];
      ax += a.x*c.x; ay += a.y*c.y; az += a.z*c.z; aw += a.w*c.w;
    }
    w[i][j] = (ax+ay+az+aw) * scale;
  }
  __syncthreads();
  if (t < nv) {
    float m = -INFINITY;
    for (int jj = 0; jj < nv; ++jj) m = fmaxf(m, w[t][jj]);
    float s = 0.f;
    for (int jj = 0; jj < nv; ++jj) { float e = expf(w[t][jj] - m); w[t][jj] = e; s += e; }
    float inv = 1.0f / s;
    for (int jj = 0; jj < nv; ++jj) w[t][jj] *= inv;
  }
  __syncthreads();
  for (int d4 = t; d4 < 40; d4 += 64) {
    for (int i2 = 0; i2 < nv; ++i2) {
      float4 a = {0.f,0.f,0.f,0.f};
      for (int j2 = 0; j2 < nv; ++j2) {
        float ww = w[i2][j2];
        float4 v4 = *(const float4*)&vb[(size_t)rows[j2]*DIMS_ + d4*4];
        a.x += ww*v4.x; a.y += ww*v4.y; a.z += ww*v4.z; a.w += ww*v4.w;
      }
      *(float4*)&ab[(size_t)rows[i2]*DIMS_ + d4*4] = a;
    }
  }
}

// ---------------- final projection ----------------
__global__ __launch_bounds__(256)
void out_kernel(const float* __restrict__ pf, const float* __restrict__ outW,
                const float* __restrict__ outB, const int* __restrict__ pk,
                float* __restrict__ out) {
  int idx = blockIdx.x*256 + threadIdx.x;
  if (idx >= BB*12*NNODES) return;
  int n = idx % NNODES;
  int rest = idx / NNODES;
  int o = rest % 12;
  int b = rest / 12;
  int row = b*NNODES + pk[n];
  const float4* Pr = (const float4*)&pf[(size_t)row*DIMS_];
  const float4* Wr = (const float4*)&outW[o*DIMS_];
  float ax=0.f, ay=0.f, az=0.f, aw=0.f;
#pragma unroll
  for (int d4 = 0; d4 < 40; ++d4) {
    float4 a = Pr[d4], c = Wr[d4];
    ax += a.x*c.x; ay += a.y*c.y; az += a.z*c.z; aw += a.w*c.w;
  }
  out[idx] = (ax+ay+az+aw) + outB[o];
}

extern "C" void kernel_launch(void* const* d_in, const int* in_sizes, int n_in,
                              void* d_out, int out_size, void* d_ws, size_t ws_size,
                              hipStream_t stream) {
  const float* x         = (const float*)d_in[0];
  const int*   te        = (const int*)d_in[1];
  const float* patch_emb = (const float*)d_in[2];
  const float* node_tab  = (const float*)d_in[3];
  const float* tod_emb   = (const float*)d_in[4];
  const float* dow_emb   = (const float*)d_in[5];
  const float* conv_W    = (const float*)d_in[6];
  const float* conv_b    = (const float*)d_in[7];
  const float* ln_scale  = (const float*)d_in[8];
  const float* ln_bias   = (const float*)d_in[9];
  const float* attn_W    = (const float*)d_in[10];
  const float* attn_b    = (const float*)d_in[11];
  const float* mlp_W1    = (const float*)d_in[12];
  const float* mlp_b1    = (const float*)d_in[13];
  const float* mlp_W2    = (const float*)d_in[14];
  const float* mlp_b2    = (const float*)d_in[15];
  const float* out_W     = (const float*)d_in[16];
  const float* out_b     = (const float*)d_in[17];

  float* out = (float*)d_out;
  float* probs_st = out + BB*12*NNODES;

  float* ws = (float*)d_ws;
  float* pf  = ws;
  float* qb  = pf  + (size_t)RMAX*DIMS_;
  float* kb  = qb  + (size_t)RMAX*DIMS_;
  float* vb  = kb  + (size_t)RMAX*DIMS_;
  float* ab2 = vb  + (size_t)RMAX*DIMS_;
  float* hb  = ab2 + (size_t)RMAX*DIMS_;
  unsigned short* wt_attn = (unsigned short*)(hb + (size_t)RMAX*HID_); // 24*25600
  unsigned short* wt_w1   = wt_attn + 614400;                          // 6*320*160
  unsigned short* wt_w2   = wt_w1   + 307200;                          // 6*160*320
  float* nsoft = (float*)(wt_w2 + 307200);
  int* patch_ids = (int*)(nsoft + NNODES*32);
  int* pk     = patch_ids + NNODES;
  int* cnt    = pk + NNODES;
  int* offs   = cnt + 8;
  int* cntmax = offs + 8;

  // weight conversion (independent; overlaps the front-end kernels)
  cvt_w_kernel<<<dim3(100,24), 256, 0, stream>>>(attn_W, wt_attn, 160, 160);
  cvt_w_kernel<<<dim3(200,6),  256, 0, stream>>>(mlp_W1, wt_w1, 160, 320);
  cvt_w_kernel<<<dim3(200,6),  256, 0, stream>>>(mlp_W2, wt_w2, 320, 160);

  patch_kernel<<<(NNODES + 127)/128, 128, 0, stream>>>(node_tab, patch_emb, probs_st, nsoft, patch_ids);
  scan_kernel<<<1, 1024, 0, stream>>>(patch_ids, pk, cnt, offs, cntmax);
  embed_kernel<<<dim3(NNODES, BB), 160, 0, stream>>>(x, te, conv_W, conv_b, tod_emb, dow_emb, nsoft, pk, pf);

  const int GX = (RMAX + 15)/16;   // 442 row tiles

  for (int l = 0; l < 3; ++l) {
    for (int a = 0; a < 2; ++a) {
      int wb = l*2 + a;
      const float* bbase = attn_b + (size_t)wb*4*DIMS_;
      const float* g0 = ln_scale + (size_t)(l*4 + a*2)*DIMS_;
      const float* b0 = ln_bias  + (size_t)(l*4 + a*2)*DIMS_;
      const float* g1 = ln_scale + (size_t)(l*4 + a*2 + 1)*DIMS_;
      const float* b1 = ln_bias  + (size_t)(l*4 + a*2 + 1)*DIMS_;
      const unsigned short* wqkv = wt_attn + (size_t)wb*4*25600;

      // QKV: LN(pf) @ {Wq,Wk,Wv} -> qb,kb,vb  (z = 0,1,2)
      mfma_mm<160,0,false,true><<<dim3(GX,2,3), 64, 0, stream>>>(
          pf, wqkv, bbase, qb, g0, b0,
          RMAX, DIMS_, 25600, (size_t)RMAX*DIMS_, DIMS_);

      if (a == 0)
        intra_attn<<<dim3(SMAX/QT, 8, BB), 256, 0, stream>>>(qb, kb, vb, ab2, cnt, offs);
      else
        inter_attn<<<dim3(NNODES, BB), 64, 0, stream>>>(qb, kb, vb, ab2, cnt, offs, cntmax);

      // proj + residual into pf
      mfma_mm<160,0,true,false><<<dim3(GX,2,1), 64, 0, stream>>>(
          ab2, wqkv + 3*25600, bbase + 3*DIMS_, pf, nullptr, nullptr,
          RMAX, DIMS_, 0, 0, 0);

      // MLP1: gelu(LN(pf) @ W1) -> hb  (z = 0,1 col slices of 320)
      mfma_mm<160,1,false,true><<<dim3(GX,2,2), 64, 0, stream>>>(
          pf, wt_w1 + (size_t)wb*320*160, mlp_b1 + (size_t)wb*HID_, hb, g1, b1,
          RMAX, HID_, 25600, 160, 160);

      // MLP2: hb @ W2 + residual into pf
      mfma_mm<320,0,true,false><<<dim3(GX,2,1), 64, 0, stream>>>(
          hb, wt_w2 + (size_t)wb*160*320, mlp_b2 + (size_t)wb*DIMS_, pf, nullptr, nullptr,
          RMAX, DIMS_, 0, 0, 0);
    }
  }

  out_kernel<<<(BB*12*NNODES + 255)/256, 256, 0, stream>>>(pf, out_W, out_b, pk, out);
}

// Round 7
// 602.049 us; speedup vs baseline: 2.8916x; 1.1431x over previous
//
#include <hip/hip_runtime.h>
#include <math.h>

#define NNODES 883
#define BB 8
#define DIMS_ 160
#define HID_ 320
#define PBB 944                 // padded rows per batch (patch offsets aligned to 8)
#define RMAX2 (BB*PBB)          // 7552 packed rows incl. padding
#define RMAXP (RMAX2+64)        // vt row stride (multiple of 8)
#define MAXT 16                 // max 16-wide j tiles (max patch size 256)

typedef __attribute__((ext_vector_type(8))) short short8v;   // 8 bf16 in 4 VGPRs
typedef __attribute__((ext_vector_type(4))) float fx4;

__device__ __forceinline__ unsigned short f2bf(float f) {
  unsigned int u = __float_as_uint(f);
  u = (u + 0x7fffu + ((u >> 16) & 1u)) >> 16;   // RNE
  return (unsigned short)u;
}
__device__ __forceinline__ float bf2f(unsigned short u) {
  return __uint_as_float(((unsigned int)u) << 16);
}

// ---------------- patch assignment ----------------
__global__ __launch_bounds__(128)
void patch_kernel(const float* __restrict__ node_table,
                  const float* __restrict__ patch_emb,
                  float* __restrict__ probs_st,
                  float* __restrict__ nsoft,
                  int* __restrict__ patch_ids) {
  int n = blockIdx.x * blockDim.x + threadIdx.x;
  if (n >= NNODES) return;
  float nt[32];
#pragma unroll
  for (int j = 0; j < 32; ++j) nt[j] = node_table[n*32 + j];
  float lg[8];
#pragma unroll
  for (int r = 0; r < 8; ++r) {
    float a = 0.f;
#pragma unroll
    for (int j = 0; j < 32; ++j) a += nt[j] * patch_emb[r*32 + j];
    lg[r] = a;
  }
  float m = lg[0];
#pragma unroll
  for (int r = 1; r < 8; ++r) m = fmaxf(m, lg[r]);
  float e[8]; float s = 0.f;
#pragma unroll
  for (int r = 0; r < 8; ++r) { e[r] = expf(lg[r] - m); s += e[r]; }
  float p[8];
#pragma unroll
  for (int r = 0; r < 8; ++r) p[r] = e[r] / s;
  int am = 0; float best = p[0];
#pragma unroll
  for (int r = 1; r < 8; ++r) if (p[r] > best) { best = p[r]; am = r; }
  patch_ids[n] = am;
#pragma unroll
  for (int r = 0; r < 8; ++r) {
    float hard = (r == am) ? 1.f : 0.f;
    probs_st[n*8 + r] = (hard - p[r]) + p[r];
  }
#pragma unroll
  for (int j = 0; j < 32; ++j) {
    float a = 0.f;
#pragma unroll
    for (int r = 0; r < 8; ++r) a += p[r] * patch_emb[r*32 + j];
    nsoft[n*32 + j] = a;
  }
}

// ---------------- parallel scan (patch offsets aligned to 8 rows) ----------------
__global__ __launch_bounds__(1024)
void scan_kernel(const int* __restrict__ patch_ids,
                 int* __restrict__ pk, int* __restrict__ cnt,
                 int* __restrict__ offs, int* __restrict__ cntmax) {
  __shared__ int pid_s[NNODES];
  __shared__ int cnt_s[8], offs_s[8];
  int t = threadIdx.x;
  if (t < 8) cnt_s[t] = 0;
  for (int n = t; n < NNODES; n += 1024) pid_s[n] = patch_ids[n];
  __syncthreads();
  int p = -1, pos = 0;
  if (t < NNODES) {
    p = pid_s[t];
    atomicAdd(&cnt_s[p], 1);
    for (int m = 0; m < t; ++m) pos += (pid_s[m] == p) ? 1 : 0;
  }
  __syncthreads();
  if (t == 0) {
    int o = 0, mx = 0;
#pragma unroll
    for (int r = 0; r < 8; ++r) {
      offs_s[r] = o; offs[r] = o; cnt[r] = cnt_s[r];
      if (cnt_s[r] > mx) mx = cnt_s[r];
      o += (cnt_s[r] + 7) & ~7;      // align each patch to 8 rows
    }
    cntmax[0] = mx;
  }
  __syncthreads();
  if (t < NNODES) pk[t] = offs_s[p] + pos;
}

// ---------------- embedding ----------------
__global__ __launch_bounds__(160)
void embed_kernel(const float* __restrict__ x, const int* __restrict__ te,
                  const float* __restrict__ convW, const float* __restrict__ convB,
                  const float* __restrict__ tod, const float* __restrict__ dow,
                  const float* __restrict__ nsoft, const int* __restrict__ pk,
                  float* __restrict__ pf) {
  int n = blockIdx.x, b = blockIdx.y, t = threadIdx.x;
  __shared__ float xs[3][12];
  if (t < 12) {
    int l = t;
    xs[0][l] = x[(b*12 + l)*NNODES + n];
    int base = ((b*12 + l)*NNODES + n)*2;
    xs[1][l] = (float)te[base]     / 288.0f;
    xs[2][l] = (float)te[base + 1] / 7.0f;
  }
  __syncthreads();
  int row = b*PBB + pk[n];
  float val;
  if (t < 64) {
    float a = convB[t];
#pragma unroll
    for (int c = 0; c < 3; ++c)
#pragma unroll
      for (int l = 0; l < 12; ++l)
        a += xs[c][l] * convW[t*36 + c*12 + l];
    val = a;
  } else if (t < 96) {
    int ti = te[((b*12 + 11)*NNODES + n)*2 + 0];
    val = tod[ti*32 + (t - 64)];
  } else if (t < 128) {
    int dw = te[((b*12 + 11)*NNODES + n)*2 + 1];
    val = dow[dw*32 + (t - 96)];
  } else {
    val = nsoft[n*32 + (t - 128)];
  }
  pf[row*DIMS_ + t] = val;
}

// ---------------- weight convert + transpose to bf16 [N][K] ----------------
__global__ __launch_bounds__(256)
void cvt_w_kernel(const float* __restrict__ src, unsigned short* __restrict__ dst,
                  int K, int N) {
  size_t base = (size_t)blockIdx.y * K * N;
  int total = K * N;
  for (int idx = blockIdx.x*256 + threadIdx.x; idx < total; idx += gridDim.x*256) {
    int n = idx / K, k = idx - n*K;
    dst[base + idx] = f2bf(src[base + (size_t)k*N + n]);
  }
}

// ---------------- MFMA matmul: one wave computes 16 rows x 80 cols ----------------
// Xv: f32 (optional fused LN) or bf16; Wt bf16 [Ntot][K]; Cv f32 (opt +=) or bf16.
// TRANSV: when z==2, write output transposed into vt[col][row] (V for attention).
template<int K, int ACT, bool RESID, bool LN, bool INBF, bool OUTBF, bool TRANSV>
__global__ __launch_bounds__(64)
void mfma_mm(const void* __restrict__ Xv, const unsigned short* __restrict__ Wt,
             const float* __restrict__ bias, void* __restrict__ Cv,
             const float* __restrict__ g, const float* __restrict__ bt,
             int M, int Cstride, size_t Wystep, size_t Cystep, int bystep) {
  constexpr int NS = K / 32;
  int lane = threadIdx.x;
  int r15  = lane & 15;
  int kg   = lane >> 4;            // 0..3
  int row0 = blockIdx.x * 16;
  int colbase = blockIdx.y * 80;
  int z = blockIdx.z;
  Wt   += (size_t)z * Wystep;
  bias += (size_t)z * bystep;

  int ar = row0 + r15; if (ar > M-1) ar = M-1;

  short8v afrag[NS];
  if (INBF) {
    const unsigned short* Xr = (const unsigned short*)Xv + (size_t)ar*K + kg*8;
#pragma unroll
    for (int t = 0; t < NS; ++t)
      afrag[t] = *(const short8v*)(const void*)(Xr + t*32);
  } else {
    const float* Xr = (const float*)Xv + (size_t)ar*K + kg*8;
    if (LN) {
      float av[8*NS];
      float s = 0.f, ss = 0.f;
#pragma unroll
      for (int t = 0; t < NS; ++t) {
        float4 v0 = *(const float4*)(Xr + t*32);
        float4 v1 = *(const float4*)(Xr + t*32 + 4);
        float* a = &av[t*8];
        a[0]=v0.x; a[1]=v0.y; a[2]=v0.z; a[3]=v0.w;
        a[4]=v1.x; a[5]=v1.y; a[6]=v1.z; a[7]=v1.w;
#pragma unroll
        for (int j = 0; j < 8; ++j) { s += a[j]; ss += a[j]*a[j]; }
      }
      s  += __shfl_xor(s, 16);  ss += __shfl_xor(ss, 16);
      s  += __shfl_xor(s, 32);  ss += __shfl_xor(ss, 32);
      float mu  = s * (1.0f/(float)K);
      float var = ss * (1.0f/(float)K) - mu*mu;
      float rsig = rsqrtf(var + 1e-5f);
#pragma unroll
      for (int t = 0; t < NS; ++t) {
        int kb = t*32 + kg*8;
        float4 g0 = *(const float4*)(g + kb);
        float4 g1 = *(const float4*)(g + kb + 4);
        float4 b0 = *(const float4*)(bt + kb);
        float4 b1 = *(const float4*)(bt + kb + 4);
        float gv[8] = {g0.x,g0.y,g0.z,g0.w,g1.x,g1.y,g1.z,g1.w};
        float bv[8] = {b0.x,b0.y,b0.z,b0.w,b1.x,b1.y,b1.z,b1.w};
        short8v f;
#pragma unroll
        for (int j = 0; j < 8; ++j) {
          float nv = (av[t*8 + j] - mu) * rsig * gv[j] + bv[j];
          f[j] = (short)f2bf(nv);
        }
        afrag[t] = f;
      }
    } else {
#pragma unroll
      for (int t = 0; t < NS; ++t) {
        float4 v0 = *(const float4*)(Xr + t*32);
        float4 v1 = *(const float4*)(Xr + t*32 + 4);
        short8v f;
        f[0]=(short)f2bf(v0.x); f[1]=(short)f2bf(v0.y);
        f[2]=(short)f2bf(v0.z); f[3]=(short)f2bf(v0.w);
        f[4]=(short)f2bf(v1.x); f[5]=(short)f2bf(v1.y);
        f[6]=(short)f2bf(v1.z); f[7]=(short)f2bf(v1.w);
        afrag[t] = f;
      }
    }
  }

  fx4 acc[5];
#pragma unroll
  for (int n = 0; n < 5; ++n) acc[n] = (fx4){0.f,0.f,0.f,0.f};

  const unsigned short* Wb = Wt + (size_t)(colbase + r15)*K + kg*8;
#pragma unroll
  for (int t = 0; t < NS; ++t) {
#pragma unroll
    for (int n = 0; n < 5; ++n) {
      short8v bfr = *(const short8v*)(const void*)(Wb + (size_t)n*16*K + t*32);
      acc[n] = __builtin_amdgcn_mfma_f32_16x16x32_bf16(afrag[t], bfr, acc[n], 0, 0, 0);
    }
  }

  int orow0 = row0 + kg*4;
#pragma unroll
  for (int n = 0; n < 5; ++n) {
    int col = colbase + n*16 + r15;
    float bv = bias[col];
#pragma unroll
    for (int i = 0; i < 4; ++i) {
      int rr = orow0 + i;
      if (rr >= M) continue;
      float v = acc[n][i] + bv;
      if (ACT == 1) v = 0.5f*v*(1.f + erff(v*0.70710678118654752f));
      if (OUTBF) {
        unsigned short* C = (unsigned short*)Cv + (size_t)z * Cystep;
        unsigned short h = f2bf(v);
        if (TRANSV && z == 2) C[(size_t)col*RMAXP + rr] = h;
        else                  C[(size_t)rr*Cstride + col] = h;
      } else {
        float* C = (float*)Cv + (size_t)z * Cystep;
        float* p = &C[(size_t)rr*Cstride + col];
        if (RESID) *p += v; else *p = v;
      }
    }
  }
}

// ---------------- intra-patch attention: 1 wave = 16 queries, full MFMA ----------------
__global__ __launch_bounds__(64)
void intra_attn_mfma(const unsigned short* __restrict__ qb,
                     const unsigned short* __restrict__ kb,
                     const unsigned short* __restrict__ vt,
                     unsigned short* __restrict__ ab,
                     const int* __restrict__ cnt, const int* __restrict__ offs) {
  int r = blockIdx.y, b = blockIdx.z;
  int L = cnt[r];
  int q0 = blockIdx.x * 16;
  if (q0 >= L) return;
  int bo = b*PBB + offs[r];
  int lane = threadIdx.x, r15 = lane & 15, kg = lane >> 4;
  const float scale = 0.07905694150420949f;   // 1/sqrt(160)

  // Q fragments (row = q0+r15, 5 k-steps of 32)
  short8v qf[5];
  {
    const unsigned short* Qr = qb + (size_t)(bo + q0 + r15)*DIMS_ + kg*8;
#pragma unroll
    for (int kk = 0; kk < 5; ++kk)
      qf[kk] = *(const short8v*)(const void*)(Qr + kk*32);
  }

  int nkt = (L + 15) >> 4;
  int npv = (L + 31) >> 5;

  // QK^T: scores in registers, s[t] holds S[q=4kg+i][j=t*16+r15]
  fx4 s[MAXT];
#pragma unroll
  for (int t = 0; t < MAXT; ++t) {
    if (t < nkt) {
      fx4 a = (fx4){0.f,0.f,0.f,0.f};
      const unsigned short* Kr = kb + (size_t)(bo + t*16 + r15)*DIMS_ + kg*8;
#pragma unroll
      for (int kk = 0; kk < 5; ++kk) {
        short8v kf = *(const short8v*)(const void*)(Kr + kk*32);
        a = __builtin_amdgcn_mfma_f32_16x16x32_bf16(qf[kk], kf, a, 0, 0, 0);
      }
      s[t] = a;
    }
  }

  // softmax (rows live across 16 lanes of the same kg group)
  float m0[4] = {-1e30f,-1e30f,-1e30f,-1e30f};
#pragma unroll
  for (int t = 0; t < MAXT; ++t) {
    if (t < nkt) {
      bool v = (t*16 + r15) < L;
#pragma unroll
      for (int i = 0; i < 4; ++i) {
        float sc = v ? s[t][i]*scale : -1e30f;
        s[t][i] = sc;
        m0[i] = fmaxf(m0[i], sc);
      }
    }
  }
#pragma unroll
  for (int i = 0; i < 4; ++i) {
    m0[i] = fmaxf(m0[i], __shfl_xor(m0[i], 1, 16));
    m0[i] = fmaxf(m0[i], __shfl_xor(m0[i], 2, 16));
    m0[i] = fmaxf(m0[i], __shfl_xor(m0[i], 4, 16));
    m0[i] = fmaxf(m0[i], __shfl_xor(m0[i], 8, 16));
  }
  float sum0[4] = {0.f,0.f,0.f,0.f};
#pragma unroll
  for (int t = 0; t < MAXT; ++t) {
    if (t < nkt) {
      bool v = (t*16 + r15) < L;
#pragma unroll
      for (int i = 0; i < 4; ++i) {
        float e = v ? expf(s[t][i] - m0[i]) : 0.f;
        s[t][i] = e; sum0[i] += e;
      }
    }
  }
#pragma unroll
  for (int i = 0; i < 4; ++i) {
    sum0[i] += __shfl_xor(sum0[i], 1, 16);
    sum0[i] += __shfl_xor(sum0[i], 2, 16);
    sum0[i] += __shfl_xor(sum0[i], 4, 16);
    sum0[i] += __shfl_xor(sum0[i], 8, 16);
  }

  // P -> XOR-swizzled LDS (bf16), then read back as A-fragments
  __shared__ unsigned short Pl[16*256];
  char* Pb = (char*)Pl;
#pragma unroll
  for (int t = 0; t < MAXT; ++t) {
    if (t < nkt) {
#pragma unroll
      for (int i = 0; i < 4; ++i) {
        int row = 4*kg + i;
        int byte = row*512 + (((t*16 + r15)*2) ^ ((row & 7) << 4));
        *(unsigned short*)(Pb + byte) = f2bf(s[t][i]);
      }
    } else if (t*16 < npv*32) {   // zero pad up to the PV 32-boundary
#pragma unroll
      for (int i = 0; i < 4; ++i) {
        int row = 4*kg + i;
        int byte = row*512 + (((t*16 + r15)*2) ^ ((row & 7) << 4));
        *(unsigned short*)(Pb + byte) = 0;
      }
    }
  }
  __syncthreads();

  // PV: O[q][d] = sum_j P[q][j] V[j][d], V^T fragments straight from global
  fx4 o[10];
#pragma unroll
  for (int n = 0; n < 10; ++n) o[n] = (fx4){0.f,0.f,0.f,0.f};
#pragma unroll
  for (int sS = 0; sS < 8; ++sS) {
    if (sS < npv) {
      short8v pfr = *(const short8v*)(const void*)
          (Pb + r15*512 + ((sS*64 + kg*16) ^ ((r15 & 7) << 4)));
#pragma unroll
      for (int n = 0; n < 10; ++n) {
        const unsigned short* Vr = vt + (size_t)(n*16 + r15)*RMAXP + bo + sS*32 + kg*8;
        short8v vf = *(const short8v*)(const void*)Vr;
        o[n] = __builtin_amdgcn_mfma_f32_16x16x32_bf16(pfr, vf, o[n], 0, 0, 0);
      }
    }
  }

  float inv[4];
#pragma unroll
  for (int i = 0; i < 4; ++i) inv[i] = 1.f / sum0[i];
#pragma unroll
  for (int n = 0; n < 10; ++n) {
    int d = n*16 + r15;
#pragma unroll
    for (int i = 0; i < 4; ++i) {
      int q = q0 + 4*kg + i;
      if (q < L) ab[(size_t)(bo + q)*DIMS_ + d] = f2bf(o[n][i]*inv[i]);
    }
  }
}

// ---------------- inter-patch attention (<=8 keys), bf16 in/out ----------------
__global__ __launch_bounds__(64)
void inter_attn(const unsigned short* __restrict__ qb,
                const unsigned short* __restrict__ kb,
                const unsigned short* __restrict__ vt,
                unsigned short* __restrict__ ab,
                const int* __restrict__ cnt, const int* __restrict__ offs,
                const int* __restrict__ cntmax) {
  int p = blockIdx.x, b = blockIdx.y;
  if (p >= cntmax[0]) return;
  int t = threadIdx.x;
  __shared__ int rows[8];
  __shared__ int nvs;
  __shared__ float w[8][9];
  if (t == 0) {
    int nv = 0;
    for (int r = 0; r < 8; ++r)
      if (p < cnt[r]) rows[nv++] = b*PBB + offs[r] + p;
    nvs = nv;
  }
  __syncthreads();
  int nv = nvs;
  const float scale = 0.07905694150420949f;
  int i = t >> 3, j = t & 7;
  if (i < nv && j < nv) {
    const unsigned short* qr = qb + (size_t)rows[i]*DIMS_;
    const unsigned short* kr = kb + (size_t)rows[j]*DIMS_;
    float a = 0.f;
#pragma unroll
    for (int d8 = 0; d8 < 20; ++d8) {
      short8v a8 = *(const short8v*)(const void*)(qr + d8*8);
      short8v b8 = *(const short8v*)(const void*)(kr + d8*8);
#pragma unroll
      for (int u = 0; u < 8; ++u)
        a += bf2f((unsigned short)a8[u]) * bf2f((unsigned short)b8[u]);
    }
    w[i][j] = a * scale;
  }
  __syncthreads();
  if (t < nv) {
    float m = -INFINITY;
    for (int jj = 0; jj < nv; ++jj) m = fmaxf(m, w[t][jj]);
    float s = 0.f;
    for (int jj = 0; jj < nv; ++jj) { float e = expf(w[t][jj] - m); w[t][jj] = e; s += e; }
    float inv = 1.0f / s;
    for (int jj = 0; jj < nv; ++jj) w[t][jj] *= inv;
  }
  __syncthreads();
  for (int d = t; d < 160; d += 64) {
    for (int i2 = 0; i2 < nv; ++i2) {
      float a = 0.f;
      for (int j2 = 0; j2 < nv; ++j2)
        a += w[i2][j2] * bf2f(vt[(size_t)d*RMAXP + rows[j2]]);
      ab[(size_t)rows[i2]*DIMS_ + d] = f2bf(a);
    }
  }
}

// ---------------- final projection ----------------
__global__ __launch_bounds__(256)
void out_kernel(const float* __restrict__ pf, const float* __restrict__ outW,
                const float* __restrict__ outB, const int* __restrict__ pk,
                float* __restrict__ out) {
  int idx = blockIdx.x*256 + threadIdx.x;
  if (idx >= BB*12*NNODES) return;
  int n = idx % NNODES;
  int rest = idx / NNODES;
  int o = rest % 12;
  int b = rest / 12;
  int row = b*PBB + pk[n];
  const float4* Pr = (const float4*)&pf[(size_t)row*DIMS_];
  const float4* Wr = (const float4*)&outW[o*DIMS_];
  float ax=0.f, ay=0.f, az=0.f, aw=0.f;
#pragma unroll
  for (int d4 = 0; d4 < 40; ++d4) {
    float4 a = Pr[d4], c = Wr[d4];
    ax += a.x*c.x; ay += a.y*c.y; az += a.z*c.z; aw += a.w*c.w;
  }
  out[idx] = (ax+ay+az+aw) + outB[o];
}

extern "C" void kernel_launch(void* const* d_in, const int* in_sizes, int n_in,
                              void* d_out, int out_size, void* d_ws, size_t ws_size,
                              hipStream_t stream) {
  const float* x         = (const float*)d_in[0];
  const int*   te        = (const int*)d_in[1];
  const float* patch_emb = (const float*)d_in[2];
  const float* node_tab  = (const float*)d_in[3];
  const float* tod_emb   = (const float*)d_in[4];
  const float* dow_emb   = (const float*)d_in[5];
  const float* conv_W    = (const float*)d_in[6];
  const float* conv_b    = (const float*)d_in[7];
  const float* ln_scale  = (const float*)d_in[8];
  const float* ln_bias   = (const float*)d_in[9];
  const float* attn_W    = (const float*)d_in[10];
  const float* attn_b    = (const float*)d_in[11];
  const float* mlp_W1    = (const float*)d_in[12];
  const float* mlp_b1    = (const float*)d_in[13];
  const float* mlp_W2    = (const float*)d_in[14];
  const float* mlp_b2    = (const float*)d_in[15];
  const float* out_W     = (const float*)d_in[16];
  const float* out_b     = (const float*)d_in[17];

  float* out = (float*)d_out;
  float* probs_st = out + BB*12*NNODES;

  const size_t CY = (size_t)(RMAX2 + 16) * DIMS_;   // q/k slice stride (ushorts)

  char* W = (char*)d_ws;
  float* pf = (float*)W;                        W += (size_t)RMAX2*DIMS_*4;
  unsigned short* qb = (unsigned short*)W;      W += CY*2;                       // q
  unsigned short* kb = (unsigned short*)W;      W += CY*2;                       // k
  unsigned short* vt = (unsigned short*)W;      W += (size_t)DIMS_*RMAXP*2;      // v^T
  unsigned short* ab = (unsigned short*)W;      W += CY*2;
  unsigned short* hb = (unsigned short*)W;      W += (size_t)RMAX2*HID_*2;
  unsigned short* wt_attn = (unsigned short*)W; W += (size_t)24*160*160*2;
  unsigned short* wt_w1   = (unsigned short*)W; W += (size_t)6*320*160*2;
  unsigned short* wt_w2   = (unsigned short*)W; W += (size_t)6*160*320*2;
  float* nsoft = (float*)W;                     W += (size_t)NNODES*32*4;
  int* patch_ids = (int*)W;
  int* pk     = patch_ids + NNODES;
  int* cnt    = pk + NNODES;
  int* offs   = cnt + 8;
  int* cntmax = offs + 8;

  // weight conversion (independent; overlaps front-end)
  cvt_w_kernel<<<dim3(100,24), 256, 0, stream>>>(attn_W, wt_attn, 160, 160);
  cvt_w_kernel<<<dim3(200,6),  256, 0, stream>>>(mlp_W1, wt_w1, 160, 320);
  cvt_w_kernel<<<dim3(200,6),  256, 0, stream>>>(mlp_W2, wt_w2, 320, 160);

  patch_kernel<<<(NNODES + 127)/128, 128, 0, stream>>>(node_tab, patch_emb, probs_st, nsoft, patch_ids);
  scan_kernel<<<1, 1024, 0, stream>>>(patch_ids, pk, cnt, offs, cntmax);
  embed_kernel<<<dim3(NNODES, BB), 160, 0, stream>>>(x, te, conv_W, conv_b, tod_emb, dow_emb, nsoft, pk, pf);

  const int GX = RMAX2 / 16;   // 472 row tiles

  for (int l = 0; l < 3; ++l) {
    for (int a = 0; a < 2; ++a) {
      int wb = l*2 + a;
      const float* bbase = attn_b + (size_t)wb*4*DIMS_;
      const float* g0 = ln_scale + (size_t)(l*4 + a*2)*DIMS_;
      const float* b0 = ln_bias  + (size_t)(l*4 + a*2)*DIMS_;
      const float* g1 = ln_scale + (size_t)(l*4 + a*2 + 1)*DIMS_;
      const float* b1 = ln_bias  + (size_t)(l*4 + a*2 + 1)*DIMS_;
      const unsigned short* wqkv = wt_attn + (size_t)wb*4*25600;

      // QKV: LN(pf) @ {Wq,Wk,Wv} -> qb,kb (row-major bf16), vt (transposed bf16)
      mfma_mm<160,0,false,true,false,true,true><<<dim3(GX,2,3), 64, 0, stream>>>(
          pf, wqkv, bbase, qb, g0, b0,
          RMAX2, DIMS_, 25600, CY, DIMS_);

      if (a == 0)
        intra_attn_mfma<<<dim3(16, 8, BB), 64, 0, stream>>>(qb, kb, vt, ab, cnt, offs);
      else
        inter_attn<<<dim3(NNODES, BB), 64, 0, stream>>>(qb, kb, vt, ab, cnt, offs, cntmax);

      // proj (bf16 in) + residual into pf (f32)
      mfma_mm<160,0,true,false,true,false,false><<<dim3(GX,2,1), 64, 0, stream>>>(
          ab, wqkv + 3*25600, bbase + 3*DIMS_, pf, nullptr, nullptr,
          RMAX2, DIMS_, 0, 0, 0);

      // MLP1: gelu(LN(pf) @ W1) -> hb bf16  (z = 0,1 col slices of 320)
      mfma_mm<160,1,false,true,false,true,false><<<dim3(GX,2,2), 64, 0, stream>>>(
          pf, wt_w1 + (size_t)wb*320*160, mlp_b1 + (size_t)wb*HID_, hb, g1, b1,
          RMAX2, HID_, 25600, 160, 160);

      // MLP2: hb(bf16) @ W2 + residual into pf (f32)
      mfma_mm<320,0,true,false,true,false,false><<<dim3(GX,2,1), 64, 0, stream>>>(
          hb, wt_w2 + (size_t)wb*160*320, mlp_b2 + (size_t)wb*DIMS_, pf, nullptr, nullptr,
          RMAX2, DIMS_, 0, 0, 0);
    }
  }

  out_kernel<<<(BB*12*NNODES + 255)/256, 256, 0, stream>>>(pf, out_W, out_b, pk, out);
}

// Round 8
// 476.134 us; speedup vs baseline: 3.6562x; 1.2645x over previous
//
#include <hip/hip_runtime.h>
#include <math.h>

#define NNODES 883
#define BB 8
#define DIMS_ 160
#define HID_ 320
#define PBB 944                 // padded rows per batch (patch offsets aligned to 8)
#define RMAX2 (BB*PBB)          // 7552 packed rows incl. padding
#define RMAXP (RMAX2+64)        // vt row stride (multiple of 8)
#define MAXT 16                 // max 16-wide j tiles (max patch size 256)

typedef __attribute__((ext_vector_type(8))) short short8v;   // 8 bf16 in 4 VGPRs
typedef __attribute__((ext_vector_type(4))) float fx4;
typedef __attribute__((ext_vector_type(4))) unsigned short ushort4v;

__device__ __forceinline__ unsigned short f2bf(float f) {
  unsigned int u = __float_as_uint(f);
  u = (u + 0x7fffu + ((u >> 16) & 1u)) >> 16;   // RNE
  return (unsigned short)u;
}
__device__ __forceinline__ float bf2f(unsigned short u) {
  return __uint_as_float(((unsigned int)u) << 16);
}

// ---------------- patch assignment ----------------
__global__ __launch_bounds__(128)
void patch_kernel(const float* __restrict__ node_table,
                  const float* __restrict__ patch_emb,
                  float* __restrict__ probs_st,
                  float* __restrict__ nsoft,
                  int* __restrict__ patch_ids) {
  int n = blockIdx.x * blockDim.x + threadIdx.x;
  if (n >= NNODES) return;
  float nt[32];
#pragma unroll
  for (int j = 0; j < 32; ++j) nt[j] = node_table[n*32 + j];
  float lg[8];
#pragma unroll
  for (int r = 0; r < 8; ++r) {
    float a = 0.f;
#pragma unroll
    for (int j = 0; j < 32; ++j) a += nt[j] * patch_emb[r*32 + j];
    lg[r] = a;
  }
  float m = lg[0];
#pragma unroll
  for (int r = 1; r < 8; ++r) m = fmaxf(m, lg[r]);
  float e[8]; float s = 0.f;
#pragma unroll
  for (int r = 0; r < 8; ++r) { e[r] = expf(lg[r] - m); s += e[r]; }
  float p[8];
#pragma unroll
  for (int r = 0; r < 8; ++r) p[r] = e[r] / s;
  int am = 0; float best = p[0];
#pragma unroll
  for (int r = 1; r < 8; ++r) if (p[r] > best) { best = p[r]; am = r; }
  patch_ids[n] = am;
#pragma unroll
  for (int r = 0; r < 8; ++r) {
    float hard = (r == am) ? 1.f : 0.f;
    probs_st[n*8 + r] = (hard - p[r]) + p[r];
  }
#pragma unroll
  for (int j = 0; j < 32; ++j) {
    float a = 0.f;
#pragma unroll
    for (int r = 0; r < 8; ++r) a += p[r] * patch_emb[r*32 + j];
    nsoft[n*32 + j] = a;
  }
}

// ---------------- parallel scan (patch offsets aligned to 8 rows) ----------------
__global__ __launch_bounds__(1024)
void scan_kernel(const int* __restrict__ patch_ids,
                 int* __restrict__ pk, int* __restrict__ cnt,
                 int* __restrict__ offs, int* __restrict__ cntmax) {
  __shared__ int pid_s[NNODES];
  __shared__ int cnt_s[8], offs_s[8];
  int t = threadIdx.x;
  if (t < 8) cnt_s[t] = 0;
  for (int n = t; n < NNODES; n += 1024) pid_s[n] = patch_ids[n];
  __syncthreads();
  int p = -1, pos = 0;
  if (t < NNODES) {
    p = pid_s[t];
    atomicAdd(&cnt_s[p], 1);
    for (int m = 0; m < t; ++m) pos += (pid_s[m] == p) ? 1 : 0;
  }
  __syncthreads();
  if (t == 0) {
    int o = 0, mx = 0;
#pragma unroll
    for (int r = 0; r < 8; ++r) {
      offs_s[r] = o; offs[r] = o; cnt[r] = cnt_s[r];
      if (cnt_s[r] > mx) mx = cnt_s[r];
      o += (cnt_s[r] + 7) & ~7;      // align each patch to 8 rows
    }
    cntmax[0] = mx;
  }
  __syncthreads();
  if (t < NNODES) pk[t] = offs_s[p] + pos;
}

// ---------------- embedding ----------------
__global__ __launch_bounds__(160)
void embed_kernel(const float* __restrict__ x, const int* __restrict__ te,
                  const float* __restrict__ convW, const float* __restrict__ convB,
                  const float* __restrict__ tod, const float* __restrict__ dow,
                  const float* __restrict__ nsoft, const int* __restrict__ pk,
                  float* __restrict__ pf) {
  int n = blockIdx.x, b = blockIdx.y, t = threadIdx.x;
  __shared__ float xs[3][12];
  if (t < 12) {
    int l = t;
    xs[0][l] = x[(b*12 + l)*NNODES + n];
    int base = ((b*12 + l)*NNODES + n)*2;
    xs[1][l] = (float)te[base]     / 288.0f;
    xs[2][l] = (float)te[base + 1] / 7.0f;
  }
  __syncthreads();
  int row = b*PBB + pk[n];
  float val;
  if (t < 64) {
    float a = convB[t];
#pragma unroll
    for (int c = 0; c < 3; ++c)
#pragma unroll
      for (int l = 0; l < 12; ++l)
        a += xs[c][l] * convW[t*36 + c*12 + l];
    val = a;
  } else if (t < 96) {
    int ti = te[((b*12 + 11)*NNODES + n)*2 + 0];
    val = tod[ti*32 + (t - 64)];
  } else if (t < 128) {
    int dw = te[((b*12 + 11)*NNODES + n)*2 + 1];
    val = dow[dw*32 + (t - 96)];
  } else {
    val = nsoft[n*32 + (t - 128)];
  }
  pf[row*DIMS_ + t] = val;
}

// ---------------- weight convert + transpose to bf16 [N][K] ----------------
__global__ __launch_bounds__(256)
void cvt_w_kernel(const float* __restrict__ src, unsigned short* __restrict__ dst,
                  int K, int N) {
  size_t base = (size_t)blockIdx.y * K * N;
  int total = K * N;
  for (int idx = blockIdx.x*256 + threadIdx.x; idx < total; idx += gridDim.x*256) {
    int n = idx / K, k = idx - n*K;
    dst[base + idx] = f2bf(src[base + (size_t)k*N + n]);
  }
}

// ---------------- MFMA matmul: one wave computes 16 rows x (CT*16) cols ----------------
// Xv: f32 (optional fused LN) or bf16; Wt bf16 [Ntot][K]; Cv f32 (opt +=) or bf16.
// TRANSV: when z==2, write output transposed into vt[col][row] (V for intra attention).
template<int K, int ACT, bool RESID, bool LN, bool INBF, bool OUTBF, bool TRANSV, int CT>
__global__ __launch_bounds__(64)
void mfma_mm(const void* __restrict__ Xv, const unsigned short* __restrict__ Wt,
             const float* __restrict__ bias, void* __restrict__ Cv,
             const float* __restrict__ g, const float* __restrict__ bt,
             int M, int Cstride, size_t Wystep, size_t Cystep, int bystep) {
  constexpr int NS = K / 32;
  int lane = threadIdx.x;
  int r15  = lane & 15;
  int kg   = lane >> 4;            // 0..3
  int row0 = blockIdx.x * 16;
  int colbase = blockIdx.y * (CT*16);
  int z = blockIdx.z;
  Wt   += (size_t)z * Wystep;
  bias += (size_t)z * bystep;

  int ar = row0 + r15; if (ar > M-1) ar = M-1;

  short8v afrag[NS];
  if (INBF) {
    const unsigned short* Xr = (const unsigned short*)Xv + (size_t)ar*K + kg*8;
#pragma unroll
    for (int t = 0; t < NS; ++t)
      afrag[t] = *(const short8v*)(const void*)(Xr + t*32);
  } else {
    const float* Xr = (const float*)Xv + (size_t)ar*K + kg*8;
    if (LN) {
      float av[8*NS];
      float s = 0.f, ss = 0.f;
#pragma unroll
      for (int t = 0; t < NS; ++t) {
        float4 v0 = *(const float4*)(Xr + t*32);
        float4 v1 = *(const float4*)(Xr + t*32 + 4);
        float* a = &av[t*8];
        a[0]=v0.x; a[1]=v0.y; a[2]=v0.z; a[3]=v0.w;
        a[4]=v1.x; a[5]=v1.y; a[6]=v1.z; a[7]=v1.w;
#pragma unroll
        for (int j = 0; j < 8; ++j) { s += a[j]; ss += a[j]*a[j]; }
      }
      s  += __shfl_xor(s, 16);  ss += __shfl_xor(ss, 16);
      s  += __shfl_xor(s, 32);  ss += __shfl_xor(ss, 32);
      float mu  = s * (1.0f/(float)K);
      float var = ss * (1.0f/(float)K) - mu*mu;
      float rsig = rsqrtf(var + 1e-5f);
#pragma unroll
      for (int t = 0; t < NS; ++t) {
        int kb = t*32 + kg*8;
        float4 g0 = *(const float4*)(g + kb);
        float4 g1 = *(const float4*)(g + kb + 4);
        float4 b0 = *(const float4*)(bt + kb);
        float4 b1 = *(const float4*)(bt + kb + 4);
        float gv[8] = {g0.x,g0.y,g0.z,g0.w,g1.x,g1.y,g1.z,g1.w};
        float bv[8] = {b0.x,b0.y,b0.z,b0.w,b1.x,b1.y,b1.z,b1.w};
        short8v f;
#pragma unroll
        for (int j = 0; j < 8; ++j) {
          float nv = (av[t*8 + j] - mu) * rsig * gv[j] + bv[j];
          f[j] = (short)f2bf(nv);
        }
        afrag[t] = f;
      }
    } else {
#pragma unroll
      for (int t = 0; t < NS; ++t) {
        float4 v0 = *(const float4*)(Xr + t*32);
        float4 v1 = *(const float4*)(Xr + t*32 + 4);
        short8v f;
        f[0]=(short)f2bf(v0.x); f[1]=(short)f2bf(v0.y);
        f[2]=(short)f2bf(v0.z); f[3]=(short)f2bf(v0.w);
        f[4]=(short)f2bf(v1.x); f[5]=(short)f2bf(v1.y);
        f[6]=(short)f2bf(v1.z); f[7]=(short)f2bf(v1.w);
        afrag[t] = f;
      }
    }
  }

  fx4 acc[CT];
#pragma unroll
  for (int n = 0; n < CT; ++n) acc[n] = (fx4){0.f,0.f,0.f,0.f};

  const unsigned short* Wb = Wt + (size_t)(colbase + r15)*K + kg*8;
#pragma unroll
  for (int t = 0; t < NS; ++t) {
#pragma unroll
    for (int n = 0; n < CT; ++n) {
      short8v bfr = *(const short8v*)(const void*)(Wb + (size_t)n*16*K + t*32);
      acc[n] = __builtin_amdgcn_mfma_f32_16x16x32_bf16(afrag[t], bfr, acc[n], 0, 0, 0);
    }
  }

  int orow0 = row0 + kg*4;
#pragma unroll
  for (int n = 0; n < CT; ++n) {
    int col = colbase + n*16 + r15;
    float bv = bias[col];
#pragma unroll
    for (int i = 0; i < 4; ++i) {
      int rr = orow0 + i;
      if (rr >= M) continue;
      float v = acc[n][i] + bv;
      if (ACT == 1) v = 0.5f*v*(1.f + erff(v*0.70710678118654752f));
      if (OUTBF) {
        unsigned short* C = (unsigned short*)Cv + (size_t)z * Cystep;
        unsigned short h = f2bf(v);
        if (TRANSV && z == 2) C[(size_t)col*RMAXP + rr] = h;
        else                  C[(size_t)rr*Cstride + col] = h;
      } else {
        float* C = (float*)Cv + (size_t)z * Cystep;
        float* p = &C[(size_t)rr*Cstride + col];
        if (RESID) *p += v; else *p = v;
      }
    }
  }
}

// ---------------- intra-patch attention: 1 wave = 16 queries, full MFMA ----------------
__global__ __launch_bounds__(64)
void intra_attn_mfma(const unsigned short* __restrict__ qb,
                     const unsigned short* __restrict__ kb,
                     const unsigned short* __restrict__ vt,
                     unsigned short* __restrict__ ab,
                     const int* __restrict__ cnt, const int* __restrict__ offs) {
  int r = blockIdx.y, b = blockIdx.z;
  int L = cnt[r];
  int q0 = blockIdx.x * 16;
  if (q0 >= L) return;
  int bo = b*PBB + offs[r];
  int lane = threadIdx.x, r15 = lane & 15, kg = lane >> 4;
  const float scale = 0.07905694150420949f;   // 1/sqrt(160)

  // Q fragments (row = q0+r15, 5 k-steps of 32)
  short8v qf[5];
  {
    const unsigned short* Qr = qb + (size_t)(bo + q0 + r15)*DIMS_ + kg*8;
#pragma unroll
    for (int kk = 0; kk < 5; ++kk)
      qf[kk] = *(const short8v*)(const void*)(Qr + kk*32);
  }

  int nkt = (L + 15) >> 4;
  int npv = (L + 31) >> 5;

  // QK^T: scores in registers, s[t] holds S[q=4kg+i][j=t*16+r15]
  fx4 s[MAXT];
#pragma unroll
  for (int t = 0; t < MAXT; ++t) {
    if (t < nkt) {
      fx4 a = (fx4){0.f,0.f,0.f,0.f};
      const unsigned short* Kr = kb + (size_t)(bo + t*16 + r15)*DIMS_ + kg*8;
#pragma unroll
      for (int kk = 0; kk < 5; ++kk) {
        short8v kf = *(const short8v*)(const void*)(Kr + kk*32);
        a = __builtin_amdgcn_mfma_f32_16x16x32_bf16(qf[kk], kf, a, 0, 0, 0);
      }
      s[t] = a;
    }
  }

  // softmax (rows live across 16 lanes of the same kg group)
  float m0[4] = {-1e30f,-1e30f,-1e30f,-1e30f};
#pragma unroll
  for (int t = 0; t < MAXT; ++t) {
    if (t < nkt) {
      bool v = (t*16 + r15) < L;
#pragma unroll
      for (int i = 0; i < 4; ++i) {
        float sc = v ? s[t][i]*scale : -1e30f;
        s[t][i] = sc;
        m0[i] = fmaxf(m0[i], sc);
      }
    }
  }
#pragma unroll
  for (int i = 0; i < 4; ++i) {
    m0[i] = fmaxf(m0[i], __shfl_xor(m0[i], 1, 16));
    m0[i] = fmaxf(m0[i], __shfl_xor(m0[i], 2, 16));
    m0[i] = fmaxf(m0[i], __shfl_xor(m0[i], 4, 16));
    m0[i] = fmaxf(m0[i], __shfl_xor(m0[i], 8, 16));
  }
  float sum0[4] = {0.f,0.f,0.f,0.f};
#pragma unroll
  for (int t = 0; t < MAXT; ++t) {
    if (t < nkt) {
      bool v = (t*16 + r15) < L;
#pragma unroll
      for (int i = 0; i < 4; ++i) {
        float e = v ? expf(s[t][i] - m0[i]) : 0.f;
        s[t][i] = e; sum0[i] += e;
      }
    }
  }
#pragma unroll
  for (int i = 0; i < 4; ++i) {
    sum0[i] += __shfl_xor(sum0[i], 1, 16);
    sum0[i] += __shfl_xor(sum0[i], 2, 16);
    sum0[i] += __shfl_xor(sum0[i], 4, 16);
    sum0[i] += __shfl_xor(sum0[i], 8, 16);
  }

  // P -> XOR-swizzled LDS (bf16), then read back as A-fragments
  __shared__ unsigned short Pl[16*256];
  char* Pb = (char*)Pl;
#pragma unroll
  for (int t = 0; t < MAXT; ++t) {
    if (t < nkt) {
#pragma unroll
      for (int i = 0; i < 4; ++i) {
        int row = 4*kg + i;
        int byte = row*512 + (((t*16 + r15)*2) ^ ((row & 7) << 4));
        *(unsigned short*)(Pb + byte) = f2bf(s[t][i]);
      }
    } else if (t*16 < npv*32) {   // zero pad up to the PV 32-boundary
#pragma unroll
      for (int i = 0; i < 4; ++i) {
        int row = 4*kg + i;
        int byte = row*512 + (((t*16 + r15)*2) ^ ((row & 7) << 4));
        *(unsigned short*)(Pb + byte) = 0;
      }
    }
  }
  __syncthreads();

  // PV: O[q][d] = sum_j P[q][j] V[j][d], V^T fragments straight from global
  fx4 o[10];
#pragma unroll
  for (int n = 0; n < 10; ++n) o[n] = (fx4){0.f,0.f,0.f,0.f};
#pragma unroll
  for (int sS = 0; sS < 8; ++sS) {
    if (sS < npv) {
      short8v pfr = *(const short8v*)(const void*)
          (Pb + r15*512 + ((sS*64 + kg*16) ^ ((r15 & 7) << 4)));
#pragma unroll
      for (int n = 0; n < 10; ++n) {
        const unsigned short* Vr = vt + (size_t)(n*16 + r15)*RMAXP + bo + sS*32 + kg*8;
        short8v vf = *(const short8v*)(const void*)Vr;
        o[n] = __builtin_amdgcn_mfma_f32_16x16x32_bf16(pfr, vf, o[n], 0, 0, 0);
      }
    }
  }

  float inv[4];
#pragma unroll
  for (int i = 0; i < 4; ++i) inv[i] = 1.f / sum0[i];
#pragma unroll
  for (int n = 0; n < 10; ++n) {
    int d = n*16 + r15;
#pragma unroll
    for (int i = 0; i < 4; ++i) {
      int q = q0 + 4*kg + i;
      if (q < L) ab[(size_t)(bo + q)*DIMS_ + d] = f2bf(o[n][i]*inv[i]);
    }
  }
}

// ---------------- inter-patch attention (<=8 keys), in-register, coalesced ----------------
// V is ROW-MAJOR bf16 here (vb). One wave per (position p, batch b).
__global__ __launch_bounds__(64)
void inter_attn(const unsigned short* __restrict__ qb,
                const unsigned short* __restrict__ kb,
                const unsigned short* __restrict__ vb,
                unsigned short* __restrict__ ab,
                const int* __restrict__ cnt, const int* __restrict__ offs,
                const int* __restrict__ cntmax) {
  int p = blockIdx.x, b = blockIdx.y;
  if (p >= cntmax[0]) return;
  int t = threadIdx.x;
  int i = t >> 3, j = t & 7;
  int cnti = cnt[i], cntj = cnt[j];
  int offi = offs[i], offj = offs[j];
  bool vi = p < cnti, vj = p < cntj;
  const float scale = 0.07905694150420949f;

  // score for pair (i,j); clamp invalid rows to a safe in-bounds address
  int rowi = b*PBB + (vi ? offi + p : 0);
  int rowj = b*PBB + (vj ? offj + p : 0);
  float sc;
  {
    const short8v* qr = (const short8v*)(qb + (size_t)rowi*DIMS_);
    const short8v* kr = (const short8v*)(kb + (size_t)rowj*DIMS_);
    float a = 0.f;
#pragma unroll
    for (int d8 = 0; d8 < 20; ++d8) {
      short8v a8 = qr[d8], b8 = kr[d8];
#pragma unroll
      for (int u = 0; u < 8; ++u)
        a += bf2f((unsigned short)a8[u]) * bf2f((unsigned short)b8[u]);
    }
    sc = (vi && vj) ? a * scale : -1e30f;
  }

  // softmax across j within each 8-lane group, weights stay in registers
  float m = sc;
  m = fmaxf(m, __shfl_xor(m, 1, 8));
  m = fmaxf(m, __shfl_xor(m, 2, 8));
  m = fmaxf(m, __shfl_xor(m, 4, 8));
  float e = (vi && vj) ? expf(sc - m) : 0.f;
  float ssum = e;
  ssum += __shfl_xor(ssum, 1, 8);
  ssum += __shfl_xor(ssum, 2, 8);
  ssum += __shfl_xor(ssum, 4, 8);
  float w = vi ? e / ssum : 0.f;

  // PV: lanes 0..39 each own 4 dims; V rows coalesced 8B loads
  bool act = t < 40;
  int d0 = t * 4;
  float vv[8][4];
#pragma unroll
  for (int j2 = 0; j2 < 8; ++j2) {
    int oj2 = __shfl(offj, j2);        // offs[j2]
    int cj2 = __shfl(cntj, j2);        // cnt[j2]
    int rj2 = b*PBB + ((p < cj2) ? oj2 + p : 0);
    ushort4v v4 = {0,0,0,0};
    if (act) v4 = *(const ushort4v*)(const void*)(vb + (size_t)rj2*DIMS_ + d0);
    vv[j2][0] = bf2f(v4[0]); vv[j2][1] = bf2f(v4[1]);
    vv[j2][2] = bf2f(v4[2]); vv[j2][3] = bf2f(v4[3]);
  }
#pragma unroll
  for (int i2 = 0; i2 < 8; ++i2) {
    float a0=0.f, a1=0.f, a2=0.f, a3=0.f;
#pragma unroll
    for (int j2 = 0; j2 < 8; ++j2) {
      float wv = __shfl(w, i2*8 + j2);
      a0 += wv*vv[j2][0]; a1 += wv*vv[j2][1];
      a2 += wv*vv[j2][2]; a3 += wv*vv[j2][3];
    }
    int ci2 = __shfl(cnti, i2*8);      // cnt[i2]
    int oi2 = __shfl(offi, i2*8);      // offs[i2]
    if (act && p < ci2) {
      ushort4v h;
      h[0]=f2bf(a0); h[1]=f2bf(a1); h[2]=f2bf(a2); h[3]=f2bf(a3);
      *(ushort4v*)(void*)(ab + (size_t)(b*PBB + oi2 + p)*DIMS_ + d0) = h;
    }
  }
}

// ---------------- final projection ----------------
__global__ __launch_bounds__(256)
void out_kernel(const float* __restrict__ pf, const float* __restrict__ outW,
                const float* __restrict__ outB, const int* __restrict__ pk,
                float* __restrict__ out) {
  int idx = blockIdx.x*256 + threadIdx.x;
  if (idx >= BB*12*NNODES) return;
  int n = idx % NNODES;
  int rest = idx / NNODES;
  int o = rest % 12;
  int b = rest / 12;
  int row = b*PBB + pk[n];
  const float4* Pr = (const float4*)&pf[(size_t)row*DIMS_];
  const float4* Wr = (const float4*)&outW[o*DIMS_];
  float ax=0.f, ay=0.f, az=0.f, aw=0.f;
#pragma unroll
  for (int d4 = 0; d4 < 40; ++d4) {
    float4 a = Pr[d4], c = Wr[d4];
    ax += a.x*c.x; ay += a.y*c.y; az += a.z*c.z; aw += a.w*c.w;
  }
  out[idx] = (ax+ay+az+aw) + outB[o];
}

extern "C" void kernel_launch(void* const* d_in, const int* in_sizes, int n_in,
                              void* d_out, int out_size, void* d_ws, size_t ws_size,
                              hipStream_t stream) {
  const float* x         = (const float*)d_in[0];
  const int*   te        = (const int*)d_in[1];
  const float* patch_emb = (const float*)d_in[2];
  const float* node_tab  = (const float*)d_in[3];
  const float* tod_emb   = (const float*)d_in[4];
  const float* dow_emb   = (const float*)d_in[5];
  const float* conv_W    = (const float*)d_in[6];
  const float* conv_b    = (const float*)d_in[7];
  const float* ln_scale  = (const float*)d_in[8];
  const float* ln_bias   = (const float*)d_in[9];
  const float* attn_W    = (const float*)d_in[10];
  const float* attn_b    = (const float*)d_in[11];
  const float* mlp_W1    = (const float*)d_in[12];
  const float* mlp_b1    = (const float*)d_in[13];
  const float* mlp_W2    = (const float*)d_in[14];
  const float* mlp_b2    = (const float*)d_in[15];
  const float* out_W     = (const float*)d_in[16];
  const float* out_b     = (const float*)d_in[17];

  float* out = (float*)d_out;
  float* probs_st = out + BB*12*NNODES;

  const size_t CY = (size_t)(RMAX2 + 16) * DIMS_;   // q/k slice stride (ushorts)

  char* W = (char*)d_ws;
  float* pf = (float*)W;                        W += (size_t)RMAX2*DIMS_*4;
  unsigned short* qb = (unsigned short*)W;      W += CY*2;                       // q
  unsigned short* kb = (unsigned short*)W;      W += CY*2;                       // k
  unsigned short* vt = (unsigned short*)W;      W += (size_t)DIMS_*RMAXP*2;      // v^T or v row-major
  unsigned short* ab = (unsigned short*)W;      W += CY*2;
  unsigned short* hb = (unsigned short*)W;      W += (size_t)RMAX2*HID_*2;
  unsigned short* wt_attn = (unsigned short*)W; W += (size_t)24*160*160*2;
  unsigned short* wt_w1   = (unsigned short*)W; W += (size_t)6*320*160*2;
  unsigned short* wt_w2   = (unsigned short*)W; W += (size_t)6*160*320*2;
  float* nsoft = (float*)W;                     W += (size_t)NNODES*32*4;
  int* patch_ids = (int*)W;
  int* pk     = patch_ids + NNODES;
  int* cnt    = pk + NNODES;
  int* offs   = cnt + 8;
  int* cntmax = offs + 8;

  // deterministic padding rows (NaN safety for fresh memory)
  hipMemsetAsync(pf, 0, (size_t)RMAX2*DIMS_*4, stream);

  // weight conversion (independent; overlaps front-end)
  cvt_w_kernel<<<dim3(100,24), 256, 0, stream>>>(attn_W, wt_attn, 160, 160);
  cvt_w_kernel<<<dim3(200,6),  256, 0, stream>>>(mlp_W1, wt_w1, 160, 320);
  cvt_w_kernel<<<dim3(200,6),  256, 0, stream>>>(mlp_W2, wt_w2, 320, 160);

  patch_kernel<<<(NNODES + 127)/128, 128, 0, stream>>>(node_tab, patch_emb, probs_st, nsoft, patch_ids);
  scan_kernel<<<1, 1024, 0, stream>>>(patch_ids, pk, cnt, offs, cntmax);
  embed_kernel<<<dim3(NNODES, BB), 160, 0, stream>>>(x, te, conv_W, conv_b, tod_emb, dow_emb, nsoft, pk, pf);

  const int GX = RMAX2 / 16;   // 472 row tiles

  for (int l = 0; l < 3; ++l) {
    for (int a = 0; a < 2; ++a) {
      int wb = l*2 + a;
      const float* bbase = attn_b + (size_t)wb*4*DIMS_;
      const float* g0 = ln_scale + (size_t)(l*4 + a*2)*DIMS_;
      const float* b0 = ln_bias  + (size_t)(l*4 + a*2)*DIMS_;
      const float* g1 = ln_scale + (size_t)(l*4 + a*2 + 1)*DIMS_;
      const float* b1 = ln_bias  + (size_t)(l*4 + a*2 + 1)*DIMS_;
      const unsigned short* wqkv = wt_attn + (size_t)wb*4*25600;

      // QKV: LN(pf) @ {Wq,Wk,Wv} -> qb,kb row-major; V transposed (intra) or row-major (inter)
      if (a == 0)
        mfma_mm<160,0,false,true,false,true,true,5><<<dim3(GX,2,3), 64, 0, stream>>>(
            pf, wqkv, bbase, qb, g0, b0, RMAX2, DIMS_, 25600, CY, DIMS_);
      else
        mfma_mm<160,0,false,true,false,true,false,5><<<dim3(GX,2,3), 64, 0, stream>>>(
            pf, wqkv, bbase, qb, g0, b0, RMAX2, DIMS_, 25600, CY, DIMS_);

      if (a == 0)
        intra_attn_mfma<<<dim3(16, 8, BB), 64, 0, stream>>>(qb, kb, vt, ab, cnt, offs);
      else
        inter_attn<<<dim3(NNODES, BB), 64, 0, stream>>>(qb, kb, vt, ab, cnt, offs, cntmax);

      // proj (bf16 in) + residual into pf (f32); CT=2, y=5 for TLP
      mfma_mm<160,0,true,false,true,false,false,2><<<dim3(GX,5,1), 64, 0, stream>>>(
          ab, wqkv + 3*25600, bbase + 3*DIMS_, pf, nullptr, nullptr,
          RMAX2, DIMS_, 0, 0, 0);

      // MLP1: gelu(LN(pf) @ W1) -> hb bf16  (z = 0,1 col slices of 160)
      mfma_mm<160,1,false,true,false,true,false,2><<<dim3(GX,5,2), 64, 0, stream>>>(
          pf, wt_w1 + (size_t)wb*320*160, mlp_b1 + (size_t)wb*HID_, hb, g1, b1,
          RMAX2, HID_, 25600, 160, 160);

      // MLP2: hb(bf16) @ W2 + residual into pf (f32)
      mfma_mm<320,0,true,false,true,false,false,2><<<dim3(GX,5,1), 64, 0, stream>>>(
          hb, wt_w2 + (size_t)wb*160*320, mlp_b2 + (size_t)wb*DIMS_, pf, nullptr, nullptr,
          RMAX2, DIMS_, 0, 0, 0);
    }
  }

  out_kernel<<<(BB*12*NNODES + 255)/256, 256, 0, stream>>>(pf, out_W, out_b, pk, out);
}